// Round 4
// baseline (775.828 us; speedup 1.0000x reference)
//
#include <hip/hip_runtime.h>
#include <hip/hip_bf16.h>
#include <math.h>
#include <stdint.h>

typedef __hip_bfloat16 bf16;
typedef __attribute__((ext_vector_type(8))) short short8;   // 8 x bf16 (4 VGPRs)
typedef __attribute__((ext_vector_type(4))) float f32x4;

#define NB 16384
#define HID 768
#define EPS_LN 1e-5f
#define LAM_INIT 0.2f       // 0.8 - 0.6*exp(-0.3*0)

__device__ __forceinline__ float bf2f(bf16 x){ return __bfloat162float(x); }
__device__ __forceinline__ bf16  f2bf(float x){ return __float2bfloat16(x); }

// dtype-generic scalar load (T = actual storage type of the input buffers)
template<typename T> __device__ __forceinline__ float ldv(const void* p, int i);
template<> __device__ __forceinline__ float ldv<float>(const void* p, int i){ return ((const float*)p)[i]; }
template<> __device__ __forceinline__ float ldv<bf16 >(const void* p, int i){ return bf2f(((const bf16*)p)[i]); }

template<typename T> __device__ __forceinline__ void stv(T* p, float v);
template<> __device__ __forceinline__ void stv<float>(float* p, float v){ *p = v; }
template<> __device__ __forceinline__ void stv<bf16 >(bf16*  p, float v){ *p = f2bf(v); }

__device__ __forceinline__ float wred64(float v){
  #pragma unroll
  for (int m = 1; m <= 32; m <<= 1) v += __shfl_xor(v, m, 64);
  return v;
}

// -------- dtype detector: emb_table row 8 (all zeros) sits at bytes 512..575
// iff the buffer is bf16 (9*32*2=576B); if f32 those bytes are random normals.
__global__ void detect_dtype(const void* etab, int* flag){
  const uint32_t* p = (const uint32_t*)((const char*)etab + 512);
  int v = (threadIdx.x < 16) ? (int)p[threadIdx.x] : 0;
  #pragma unroll
  for (int m = 1; m <= 32; m <<= 1) v |= __shfl_xor(v, m, 64);
  if (threadIdx.x == 0) *flag = (v == 0) ? 1 : 0;   // 1 = bf16, 0 = f32
}

// ---------------- weight transpose: (K,N) row-major -> bf16 (N,K) row-major --
template<typename T>
__device__ __forceinline__ void transpose_body(bf16 (*tile)[33], const void* src, bf16* dst){
  const int n0 = blockIdx.x*32, k0 = blockIdx.y*32;
  const int tx = threadIdx.x, ty = threadIdx.y;
  #pragma unroll
  for (int r=0;r<4;++r)
    tile[ty + 8*r][tx] = f2bf(ldv<T>(src, (k0 + ty + 8*r)*HID + n0 + tx));
  __syncthreads();
  #pragma unroll
  for (int r=0;r<4;++r)
    dst[(size_t)(n0 + ty + 8*r)*HID + k0 + tx] = tile[tx][ty + 8*r];
}

__global__ __launch_bounds__(256) void transpose_weights(
    const void* Wq, const void* Wk, const void* Wv, const void* Wo,
    bf16* __restrict__ WqkvT, bf16* __restrict__ WoT, const int* dflag)
{
  __shared__ bf16 tile[32][33];
  const int z = blockIdx.z;
  const void* src = (z==0)? Wq : (z==1)? Wk : (z==2)? Wv : Wo;
  bf16* dst = (z<3)? (WqkvT + (size_t)z*HID*HID) : WoT;
  if (*dflag) transpose_body<bf16 >(tile, src, dst);
  else        transpose_body<float>(tile, src, dst);
}

// ---------------- fused embed -> FC1 -> LayerNorm -> exact GELU --------------
template<typename T>
__device__ __forceinline__ void embed_body(
    float (*s_emb)[32], float (*s_h)[HID],
    const int* eidx, const void* conf, const void* etab, const void* W1,
    const void* b1, const void* lng, const void* lnb, bf16* hout, int tok0)
{
  const int tid = threadIdx.x;
  const int tl0 = blockIdx.x * 16;     // chunk-local token base

  for (int i = tid; i < 16*32; i += 256) {
    int t = i >> 5, e = i & 31;
    int tt = tok0 + tl0 + t;           // global token
    int id = eidx[tt]; if (id < 0) id = 8;
    float cf = ldv<T>(conf, tt);
    s_emb[t][e] = ldv<T>(etab, id*32 + e) * cf;
  }
  __syncthreads();

  float acc0[16], acc1[16], acc2[16];
  #pragma unroll
  for (int t=0;t<16;++t){ acc0[t]=0.f; acc1[t]=0.f; acc2[t]=0.f; }
  const int c0 = tid, c1 = tid+256, c2 = tid+512;
  #pragma unroll 4
  for (int e=0;e<32;++e){
    float w0 = ldv<T>(W1, e*HID+c0), w1 = ldv<T>(W1, e*HID+c1), w2 = ldv<T>(W1, e*HID+c2);
    #pragma unroll
    for (int t=0;t<16;++t){
      float em = s_emb[t][e];
      acc0[t] += em*w0; acc1[t] += em*w1; acc2[t] += em*w2;
    }
  }
  float bb0 = ldv<T>(b1,c0), bb1 = ldv<T>(b1,c1), bb2 = ldv<T>(b1,c2);
  #pragma unroll
  for (int t=0;t<16;++t){
    s_h[t][c0] = acc0[t]+bb0; s_h[t][c1] = acc1[t]+bb1; s_h[t][c2] = acc2[t]+bb2;
  }
  __syncthreads();

  const int wv = tid>>6, lane = tid&63;
  for (int t = wv; t < 16; t += 4) {
    float x[12]; float sm = 0.f, sq = 0.f;
    #pragma unroll
    for (int j=0;j<12;++j){ float xv = s_h[t][lane + 64*j]; x[j]=xv; sm += xv; sq += xv*xv; }
    sm = wred64(sm); sq = wred64(sq);
    float mu  = sm * (1.f/768.f);
    float var = sq * (1.f/768.f) - mu*mu;
    float rs  = rsqrtf(fmaxf(var, 0.f) + EPS_LN);
    #pragma unroll
    for (int j=0;j<12;++j){
      int col = lane + 64*j;
      float y  = (x[j]-mu)*rs*ldv<T>(lng,col) + ldv<T>(lnb,col);
      float ge = 0.5f*y*(1.f + erff(y*0.70710678118f));
      hout[(size_t)(tl0+t)*HID + col] = f2bf(ge);
    }
  }
}

__global__ __launch_bounds__(256) void embed_fc1_ln_gelu(
    const int* __restrict__ eidx, const void* conf, const void* etab,
    const void* W1, const void* b1, const void* lng, const void* lnb,
    bf16* __restrict__ hout, int tok0, const int* dflag)
{
  __shared__ float s_emb[16][32];
  __shared__ float s_h[16][HID];       // 48 KB
  if (*dflag) embed_body<bf16 >(s_emb, s_h, eidx, conf, etab, W1, b1, lng, lnb, hout, tok0);
  else        embed_body<float>(s_emb, s_h, eidx, conf, etab, W1, b1, lng, lnb, hout, tok0);
}

// ---------------- 128x128 MFMA GEMM (A: MxK row-major, Bt: NxK row-major) ----
template<typename OutT>
__device__ __forceinline__ void gemm_body(
    bf16* sA, bf16* sB,
    const bf16* __restrict__ A, const bf16* __restrict__ Bt, OutT* __restrict__ C,
    int K, int lda, int ldb, int ldc)
{
  const int tid = threadIdx.x;
  const int wave = tid >> 6, lane = tid & 63;
  const int m0 = blockIdx.y * 128, n0 = blockIdx.x * 128;
  const int wm = wave >> 1, wn = wave & 1;

  f32x4 acc[4][4];
  #pragma unroll
  for (int i=0;i<4;++i)
    #pragma unroll
    for (int j=0;j<4;++j) acc[i][j] = (f32x4){0.f,0.f,0.f,0.f};

  const char* Ag = (const char*)(A  + (size_t)m0 * lda);
  const char* Bg = (const char*)(Bt + (size_t)n0 * ldb);
  const int r8  = lane >> 3;          // row within 8-row group
  const int cB  = (lane & 7) * 16;    // byte offset within row (8 lanes x 16B)

  for (int kt = 0; kt < K; kt += 64) {
    short8 ta[4], tb[4];
    #pragma unroll
    for (int ii = 0; ii < 4; ++ii) {
      const int i = wave*4 + ii;      // 8-row group index 0..15
      const int row = i*8 + r8;
      ta[ii] = *(const short8*)(Ag + ((size_t)row*lda + kt)*2 + cB);
      tb[ii] = *(const short8*)(Bg + ((size_t)row*ldb + kt)*2 + cB);
    }
    #pragma unroll
    for (int ii = 0; ii < 4; ++ii) {
      const int i = wave*4 + ii;
      *(short8*)((char*)sA + i*1024 + lane*16) = ta[ii];
      *(short8*)((char*)sB + i*1024 + lane*16) = tb[ii];
    }
    __syncthreads();
    #pragma unroll
    for (int ks = 0; ks < 64; ks += 32) {
      const int kq = ks + (lane >> 4)*8;
      short8 af[4], bfv[4];
      #pragma unroll
      for (int i=0;i<4;++i)
        af[i]  = *(const short8*)&sA[(wm*64 + i*16 + (lane&15))*64 + kq];
      #pragma unroll
      for (int j=0;j<4;++j)
        bfv[j] = *(const short8*)&sB[(wn*64 + j*16 + (lane&15))*64 + kq];
      #pragma unroll
      for (int i=0;i<4;++i)
        #pragma unroll
        for (int j=0;j<4;++j)
          acc[i][j] = __builtin_amdgcn_mfma_f32_16x16x32_bf16(af[i], bfv[j], acc[i][j], 0,0,0);
    }
    __syncthreads();
  }

  const int rb = (lane>>4)*4, cb = lane & 15;   // C/D: col=lane&15, row=quad*4+reg
  #pragma unroll
  for (int i=0;i<4;++i)
    #pragma unroll
    for (int r=0;r<4;++r) {
      const int grow = m0 + wm*64 + i*16 + rb + r;
      OutT* Cp = C + (size_t)grow*ldc + n0 + wn*64 + cb;
      #pragma unroll
      for (int j=0;j<4;++j) stv<OutT>(Cp + j*16, acc[i][j][r]);
    }
}

__global__ __launch_bounds__(256) void gemm_int(
    const bf16* __restrict__ A, const bf16* __restrict__ Bt, bf16* __restrict__ C,
    int K, int lda, int ldb, int ldc)
{
  __shared__ __align__(16) bf16 sA[128*64];
  __shared__ __align__(16) bf16 sB[128*64];
  gemm_body<bf16>(sA, sB, A, Bt, C, K, lda, ldb, ldc);
}

__global__ __launch_bounds__(256) void gemm_final(
    const bf16* __restrict__ A, const bf16* __restrict__ Bt, void* C,
    int K, int lda, int ldb, int ldc, const int* dflag)
{
  __shared__ __align__(16) bf16 sA[128*64];
  __shared__ __align__(16) bf16 sB[128*64];
  if (*dflag) gemm_body<bf16 >(sA, sB, A, Bt, (bf16*)C,  K, lda, ldb, ldc);
  else        gemm_body<float>(sA, sB, A, Bt, (float*)C, K, lda, ldb, ldc);
}

// ---------------- attention: RoPE + diff-softmax + PV + RMS + padded mean ----
template<typename T>
__device__ __forceinline__ void attn_body(
    const bf16* __restrict__ qkv, const int* __restrict__ eidx,
    const void* lq1, const void* lk1, const void* lq2, const void* lk2,
    const void* subw, bf16* __restrict__ obar, int b0)
{
  const int gw = blockIdx.x*4 + (threadIdx.x>>6);
  const int bl = gw >> 3, h = gw & 7;      // chunk-local batch row, head
  const int bg = b0 + bl;                  // global batch row
  const int lane = threadIdx.x & 63;
  const int d = lane;

  float npad[3];
  #pragma unroll
  for (int s=0;s<3;++s){ int id = eidx[bg*3+s]; npad[s] = (id < 0 || id == 8) ? 0.f : 1.f; }
  float denom = npad[0]+npad[1]+npad[2]; if (denom < 1.f) denom = 1.f;

  // lambda = exp(lq1.lk1) - exp(lq2.lk2) + 0.2
  float p1 = 0.f, p2 = 0.f;
  if (d < 48){ p1 = ldv<T>(lq1,d)*ldv<T>(lk1,d); p2 = ldv<T>(lq2,d)*ldv<T>(lk2,d); }
  p1 = wred64(p1); p2 = wred64(p2);
  p1 = fminf(fmaxf(p1, -30.f), 30.f);
  p2 = fminf(fmaxf(p2, -30.f), 30.f);
  const float lam = expf(p1) - expf(p2) + LAM_INIT;

  // RoPE for this lane's pair index
  float invf = (d < 48) ? powf(10000.f, -(float)(d & ~1)/48.f) : 0.f;
  float cs[3], sn[3];
  #pragma unroll
  for (int s=0;s<3;++s){ float ang = (float)s*invf; cs[s] = cosf(ang); sn[s] = sinf(ang); }
  const float sgn = (d & 1) ? 1.f : -1.f;

  const bf16* base = qkv + (size_t)bl*3*2304;
  float qr[3][2], kr[3][2];
  #pragma unroll
  for (int s=0;s<3;++s){
    #pragma unroll
    for (int g=0; g<2; ++g){
      float qv = (d<48) ? bf2f(base[s*2304 +        (2*h+g)*48 + d]) : 0.f;
      float kv = (d<48) ? bf2f(base[s*2304 + 768 +  (2*h+g)*48 + d]) : 0.f;
      float pq = __shfl_xor(qv, 1, 64);
      float pk = __shfl_xor(kv, 1, 64);
      qr[s][g] = (d<48) ? (qv*cs[s] + sgn*pq*sn[s]) : 0.f;
      kr[s][g] = (d<48) ? (kv*cs[s] + sgn*pk*sn[s]) : 0.f;
    }
  }

  const float scale = 0.14433756729740643f;  // 48^-0.5
  float att[2][3][3];
  #pragma unroll
  for (int g=0; g<2; ++g){
    #pragma unroll
    for (int sq=0; sq<3; ++sq){
      float sc[3];
      #pragma unroll
      for (int sk=0; sk<3; ++sk){
        float pr = wred64(qr[sq][g]*kr[sk][g]);
        sc[sk] = pr*scale + (npad[sk] > 0.f ? 0.f : -1e30f);
      }
      float mx = fmaxf(sc[0], fmaxf(sc[1], sc[2]));
      float e0 = expf(sc[0]-mx), e1 = expf(sc[1]-mx), e2 = expf(sc[2]-mx);
      float inv = 1.f/(e0+e1+e2);
      att[g][sq][0]=e0*inv; att[g][sq][1]=e1*inv; att[g][sq][2]=e2*inv;
    }
  }
  float diff[3][3];
  #pragma unroll
  for (int sq=0; sq<3; ++sq)
    #pragma unroll
    for (int sk=0; sk<3; ++sk) diff[sq][sk] = att[0][sq][sk] - lam*att[1][sq][sk];

  float v0[3], v1[3];
  #pragma unroll
  for (int s=0;s<3;++s){
    v0[s] = bf2f(base[s*2304 + 1536 + h*96 + lane]);
    v1[s] = (lane<32) ? bf2f(base[s*2304 + 1536 + h*96 + 64 + lane]) : 0.f;
  }
  float sw0 = ldv<T>(subw, lane);
  float sw1 = (lane<32) ? ldv<T>(subw, 64+lane) : 0.f;

  float a0 = 0.f, a1 = 0.f;
  #pragma unroll
  for (int sq=0; sq<3; ++sq){
    float o0 = diff[sq][0]*v0[0] + diff[sq][1]*v0[1] + diff[sq][2]*v0[2];
    float o1 = diff[sq][0]*v1[0] + diff[sq][1]*v1[1] + diff[sq][2]*v1[2];
    float ss = wred64(o0*o0 + o1*o1);             // sum over 96 dims
    float rms = sqrtf(ss*(1.f/96.f) + 1e-5f);
    float kk = 0.8f / rms;                        // includes *(1-LAMBDA_INIT)
    a0 += npad[sq]*o0*kk*sw0;
    a1 += npad[sq]*o1*kk*sw1;
  }
  const float idn = 1.f/denom;
  bf16* op = obar + (size_t)bg*HID + h*96;
  op[lane] = f2bf(a0*idn);
  if (lane < 32) op[64+lane] = f2bf(a1*idn);
}

__global__ __launch_bounds__(256) void attn_kernel(
    const bf16* __restrict__ qkv, const int* __restrict__ eidx,
    const void* lq1, const void* lk1, const void* lq2, const void* lk2,
    const void* subw, bf16* __restrict__ obar, int b0, const int* dflag)
{
  if (*dflag) attn_body<bf16 >(qkv, eidx, lq1, lk1, lq2, lk2, subw, obar, b0);
  else        attn_body<float>(qkv, eidx, lq1, lk1, lq2, lk2, subw, obar, b0);
}

// ---------------- launch ----------------------------------------------------
extern "C" void kernel_launch(void* const* d_in, const int* in_sizes, int n_in,
                              void* d_out, int out_size, void* d_ws, size_t ws_size,
                              hipStream_t stream)
{
  const int*  eidx = (const int*) d_in[0];
  const void* conf = d_in[1];
  const void* etab = d_in[2];
  const void* W1   = d_in[3];
  const void* b1   = d_in[4];
  const void* lng  = d_in[5];
  const void* lnb  = d_in[6];
  const void* Wq   = d_in[7];
  const void* Wk   = d_in[8];
  const void* Wv   = d_in[9];
  const void* Wo   = d_in[10];
  const void* lq1  = d_in[11];
  const void* lk1  = d_in[12];
  const void* lq2  = d_in[13];
  const void* lk2  = d_in[14];
  const void* subw = d_in[15];

  // ws layout: [flag 256B][obar][WqkvT][WoT][hbuf][qkv]
  const size_t FLAG_B = 256ull;
  const size_t OBAR_B = 25165824ull, WQKVT_B = 3538944ull, WOT_B = 1179648ull;
  const size_t FIXED  = FLAG_B + OBAR_B + WQKVT_B + WOT_B;   // 29,884,672

  char* ws = (char*)d_ws;
  int*  dflag = (int*)ws;
  bf16* obar  = (bf16*)(ws + FLAG_B);
  bf16* WqkvT = (bf16*)(ws + FLAG_B + OBAR_B);
  bf16* WoT   = (bf16*)(ws + FLAG_B + OBAR_B + WQKVT_B);

  // largest power-of-two chunk of batch rows that fits (min 128)
  int CB = NB;
  while (CB > 128 && FIXED + (size_t)CB*18432ull > ws_size) CB >>= 1;

  bf16* hbuf = (bf16*)(ws + FIXED);
  bf16* qkv  = (bf16*)(ws + FIXED + (size_t)CB*4608ull);

  detect_dtype<<<1, 64, 0, stream>>>(etab, dflag);
  transpose_weights<<<dim3(24,24,4), dim3(32,8), 0, stream>>>(Wq, Wk, Wv, Wo, WqkvT, WoT, dflag);

  const int nchunks = NB / CB;
  const int ctok = 3*CB;                      // tokens per chunk (mult of 384)
  for (int c = 0; c < nchunks; ++c) {
    const int b0 = c*CB, tok0 = b0*3;
    embed_fc1_ln_gelu<<<ctok/16, 256, 0, stream>>>(eidx, conf, etab, W1, b1, lng, lnb, hbuf, tok0, dflag);
    gemm_int<<<dim3(2304/128, ctok/128), 256, 0, stream>>>(hbuf, WqkvT, qkv, HID, HID, HID, 2304);
    attn_kernel<<<CB*2, 256, 0, stream>>>(qkv, eidx, lq1, lk1, lq2, lk2, subw, obar, b0, dflag);
  }

  gemm_final<<<dim3(HID/128, NB/128), 256, 0, stream>>>(obar, WoT, (void*)d_out, HID, HID, HID, HID, dflag);
}

// Round 5
// 721.258 us; speedup vs baseline: 1.0757x; 1.0757x over previous
//
#include <hip/hip_runtime.h>
#include <hip/hip_bf16.h>
#include <math.h>
#include <stdint.h>

typedef __hip_bfloat16 bf16;
typedef __attribute__((ext_vector_type(8))) short short8;   // 8 x bf16 (4 VGPRs)
typedef __attribute__((ext_vector_type(4))) float f32x4;

#define NB 16384
#define HID 768
#define EPS_LN 1e-5f
#define LAM_INIT 0.2f       // 0.8 - 0.6*exp(-0.3*0)

__device__ __forceinline__ float bf2f(bf16 x){ return __bfloat162float(x); }
__device__ __forceinline__ bf16  f2bf(float x){ return __float2bfloat16(x); }

template<typename T> __device__ __forceinline__ float ldv(const void* p, int i);
template<> __device__ __forceinline__ float ldv<float>(const void* p, int i){ return ((const float*)p)[i]; }
template<> __device__ __forceinline__ float ldv<bf16 >(const void* p, int i){ return bf2f(((const bf16*)p)[i]); }

template<typename T> __device__ __forceinline__ void stv(T* p, float v);
template<> __device__ __forceinline__ void stv<float>(float* p, float v){ *p = v; }
template<> __device__ __forceinline__ void stv<bf16 >(bf16*  p, float v){ *p = f2bf(v); }

__device__ __forceinline__ void async_copy16(void* lds, const void* g){
  __builtin_amdgcn_global_load_lds(
      (const __attribute__((address_space(1))) unsigned int*)g,
      (__attribute__((address_space(3))) unsigned int*)lds, 16, 0, 0);
}

__device__ __forceinline__ float wred64(float v){
  #pragma unroll
  for (int m = 1; m <= 32; m <<= 1) v += __shfl_xor(v, m, 64);
  return v;
}

// -------- prep (1 wave): dtype detect + lambda + RoPE tables -----------------
// dtype: emb_table row 8 (all zeros) sits at bytes 512..575 iff bf16.
// ws prep block layout (floats): [0]=flag(int), [1]=lam, [16+s*64+d]=cos, [256+s*64+d]=sin
__global__ void prep_kernel(const void* etab, const void* lq1, const void* lk1,
                            const void* lq2, const void* lk2, float* prep){
  const int lane = threadIdx.x;
  const uint32_t* p = (const uint32_t*)((const char*)etab + 512);
  int v = (lane < 16) ? (int)p[lane] : 0;
  #pragma unroll
  for (int m = 1; m <= 32; m <<= 1) v |= __shfl_xor(v, m, 64);
  const int isbf = (v == 0) ? 1 : 0;
  if (lane == 0) ((int*)prep)[0] = isbf;

  float p1 = 0.f, p2 = 0.f;
  if (lane < 48){
    if (isbf){ p1 = ldv<bf16>(lq1,lane)*ldv<bf16>(lk1,lane); p2 = ldv<bf16>(lq2,lane)*ldv<bf16>(lk2,lane); }
    else     { p1 = ldv<float>(lq1,lane)*ldv<float>(lk1,lane); p2 = ldv<float>(lq2,lane)*ldv<float>(lk2,lane); }
  }
  p1 = wred64(p1); p2 = wred64(p2);
  if (lane == 0) prep[1] = expf(p1) - expf(p2) + LAM_INIT;

  float invf = (lane < 48) ? powf(10000.f, -(float)(lane & ~1)/48.f) : 0.f;
  #pragma unroll
  for (int s=0;s<3;++s){
    float ang = (float)s*invf;
    prep[16  + s*64 + lane] = cosf(ang);
    prep[256 + s*64 + lane] = sinf(ang);
  }
}

// ---------------- weight transpose: (K,N) row-major -> bf16 (N,K) row-major --
template<typename T>
__device__ __forceinline__ void transpose_body(bf16 (*tile)[33], const void* src, bf16* dst){
  const int n0 = blockIdx.x*32, k0 = blockIdx.y*32;
  const int tx = threadIdx.x, ty = threadIdx.y;
  #pragma unroll
  for (int r=0;r<4;++r)
    tile[ty + 8*r][tx] = f2bf(ldv<T>(src, (k0 + ty + 8*r)*HID + n0 + tx));
  __syncthreads();
  #pragma unroll
  for (int r=0;r<4;++r)
    dst[(size_t)(n0 + ty + 8*r)*HID + k0 + tx] = tile[tx][ty + 8*r];
}

__global__ __launch_bounds__(256) void transpose_weights(
    const void* Wq, const void* Wk, const void* Wv, const void* Wo,
    bf16* __restrict__ WqkvT, bf16* __restrict__ WoT, const float* prep)
{
  __shared__ bf16 tile[32][33];
  const int z = blockIdx.z;
  const void* src = (z==0)? Wq : (z==1)? Wk : (z==2)? Wv : Wo;
  bf16* dst = (z<3)? (WqkvT + (size_t)z*HID*HID) : WoT;
  if (((const int*)prep)[0]) transpose_body<bf16 >(tile, src, dst);
  else                       transpose_body<float>(tile, src, dst);
}

// ---------------- fused embed -> FC1 -> LayerNorm -> exact GELU --------------
template<typename T>
__device__ __forceinline__ void embed_body(
    float (*s_emb)[32], float (*s_h)[HID],
    const int* eidx, const void* conf, const void* etab, const void* W1,
    const void* b1, const void* lng, const void* lnb, bf16* hout, int tok0)
{
  const int tid = threadIdx.x;
  const int tl0 = blockIdx.x * 16;     // chunk-local token base

  for (int i = tid; i < 16*32; i += 256) {
    int t = i >> 5, e = i & 31;
    int tt = tok0 + tl0 + t;           // global token
    int id = eidx[tt]; if (id < 0) id = 8;
    float cf = ldv<T>(conf, tt);
    s_emb[t][e] = ldv<T>(etab, id*32 + e) * cf;
  }
  __syncthreads();

  float acc0[16], acc1[16], acc2[16];
  #pragma unroll
  for (int t=0;t<16;++t){ acc0[t]=0.f; acc1[t]=0.f; acc2[t]=0.f; }
  const int c0 = tid, c1 = tid+256, c2 = tid+512;
  #pragma unroll 4
  for (int e=0;e<32;++e){
    float w0 = ldv<T>(W1, e*HID+c0), w1 = ldv<T>(W1, e*HID+c1), w2 = ldv<T>(W1, e*HID+c2);
    #pragma unroll
    for (int t=0;t<16;++t){
      float em = s_emb[t][e];
      acc0[t] += em*w0; acc1[t] += em*w1; acc2[t] += em*w2;
    }
  }
  float bb0 = ldv<T>(b1,c0), bb1 = ldv<T>(b1,c1), bb2 = ldv<T>(b1,c2);
  #pragma unroll
  for (int t=0;t<16;++t){
    s_h[t][c0] = acc0[t]+bb0; s_h[t][c1] = acc1[t]+bb1; s_h[t][c2] = acc2[t]+bb2;
  }
  __syncthreads();

  const int wv = tid>>6, lane = tid&63;
  for (int t = wv; t < 16; t += 4) {
    float x[12]; float sm = 0.f, sq = 0.f;
    #pragma unroll
    for (int j=0;j<12;++j){ float xv = s_h[t][lane + 64*j]; x[j]=xv; sm += xv; sq += xv*xv; }
    sm = wred64(sm); sq = wred64(sq);
    float mu  = sm * (1.f/768.f);
    float var = sq * (1.f/768.f) - mu*mu;
    float rs  = rsqrtf(fmaxf(var, 0.f) + EPS_LN);
    #pragma unroll
    for (int j=0;j<12;++j){
      int col = lane + 64*j;
      float y  = (x[j]-mu)*rs*ldv<T>(lng,col) + ldv<T>(lnb,col);
      float ge = 0.5f*y*(1.f + erff(y*0.70710678118f));
      hout[(size_t)(tl0+t)*HID + col] = f2bf(ge);
    }
  }
}

__global__ __launch_bounds__(256) void embed_fc1_ln_gelu(
    const int* __restrict__ eidx, const void* conf, const void* etab,
    const void* W1, const void* b1, const void* lng, const void* lnb,
    bf16* __restrict__ hout, int tok0, const float* prep)
{
  __shared__ float s_emb[16][32];
  __shared__ float s_h[16][HID];       // 48 KB
  if (((const int*)prep)[0]) embed_body<bf16 >(s_emb, s_h, eidx, conf, etab, W1, b1, lng, lnb, hout, tok0);
  else                       embed_body<float>(s_emb, s_h, eidx, conf, etab, W1, b1, lng, lnb, hout, tok0);
}

// ---------------- 128x128 MFMA GEMM, m97 global_load_lds staging -------------
template<typename OutT>
__device__ __forceinline__ void gemm_body(
    bf16* sA, bf16* sB,
    const bf16* __restrict__ A, const bf16* __restrict__ Bt, OutT* __restrict__ C,
    int K, int lda, int ldb, int ldc)
{
  const int tid = threadIdx.x;
  const int wave = tid >> 6, lane = tid & 63;
  const int m0 = blockIdx.y * 128, n0 = blockIdx.x * 128;
  const int wm = wave >> 1, wn = wave & 1;

  f32x4 acc[4][4];
  #pragma unroll
  for (int i=0;i<4;++i)
    #pragma unroll
    for (int j=0;j<4;++j) acc[i][j] = (f32x4){0.f,0.f,0.f,0.f};

  const char* Ag = (const char*)(A  + (size_t)m0 * lda);
  const char* Bg = (const char*)(Bt + (size_t)n0 * ldb);
  const int r8  = lane >> 3;          // row within 8-row group
  const int cB  = (lane & 7) * 16;    // byte offset within row (8 lanes x 16B)

  for (int kt = 0; kt < K; kt += 64) {
    #pragma unroll
    for (int ii = 0; ii < 4; ++ii) {
      const int i = wave*4 + ii;      // 8-row group index 0..15
      const int row = i*8 + r8;
      // LDS dest = wave-uniform base (i*1024) + lane*16  == row-major [row][k], 128B rows
      async_copy16((char*)sA + i*1024 + lane*16, Ag + ((size_t)row*lda + kt)*2 + cB);
      async_copy16((char*)sB + i*1024 + lane*16, Bg + ((size_t)row*ldb + kt)*2 + cB);
    }
    __syncthreads();   // compiler drains vmcnt(0) before s_barrier
    #pragma unroll
    for (int ks = 0; ks < 64; ks += 32) {
      const int kq = ks + (lane >> 4)*8;
      short8 af[4], bfv[4];
      #pragma unroll
      for (int i=0;i<4;++i)
        af[i]  = *(const short8*)&sA[(wm*64 + i*16 + (lane&15))*64 + kq];
      #pragma unroll
      for (int j=0;j<4;++j)
        bfv[j] = *(const short8*)&sB[(wn*64 + j*16 + (lane&15))*64 + kq];
      #pragma unroll
      for (int i=0;i<4;++i)
        #pragma unroll
        for (int j=0;j<4;++j)
          acc[i][j] = __builtin_amdgcn_mfma_f32_16x16x32_bf16(af[i], bfv[j], acc[i][j], 0,0,0);
    }
    __syncthreads();
  }

  const int rb = (lane>>4)*4, cb = lane & 15;   // C/D: col=lane&15, row=quad*4+reg
  #pragma unroll
  for (int i=0;i<4;++i)
    #pragma unroll
    for (int r=0;r<4;++r) {
      const int grow = m0 + wm*64 + i*16 + rb + r;
      OutT* Cp = C + (size_t)grow*ldc + n0 + wn*64 + cb;
      #pragma unroll
      for (int j=0;j<4;++j) stv<OutT>(Cp + j*16, acc[i][j][r]);
    }
}

__global__ __launch_bounds__(256) void gemm_int(
    const bf16* __restrict__ A, const bf16* __restrict__ Bt, bf16* __restrict__ C,
    int K, int lda, int ldb, int ldc)
{
  __shared__ __align__(16) bf16 sA[128*64];
  __shared__ __align__(16) bf16 sB[128*64];
  gemm_body<bf16>(sA, sB, A, Bt, C, K, lda, ldb, ldc);
}

__global__ __launch_bounds__(256) void gemm_final(
    const bf16* __restrict__ A, const bf16* __restrict__ Bt, void* C,
    int K, int lda, int ldb, int ldc, const float* prep)
{
  __shared__ __align__(16) bf16 sA[128*64];
  __shared__ __align__(16) bf16 sB[128*64];
  if (((const int*)prep)[0]) gemm_body<bf16 >(sA, sB, A, Bt, (bf16*)C,  K, lda, ldb, ldc);
  else                       gemm_body<float>(sA, sB, A, Bt, (float*)C, K, lda, ldb, ldc);
}

// ---------------- attention: RoPE + diff-softmax + PV + RMS + padded mean ----
template<typename T>
__device__ __forceinline__ void attn_body(
    const bf16* __restrict__ qkv, const int* __restrict__ eidx,
    const void* subw, bf16* __restrict__ obar, int b0, const float* prep)
{
  const int gw = blockIdx.x*4 + (threadIdx.x>>6);
  const int bl = gw >> 3, h = gw & 7;      // chunk-local batch row, head
  const int bg = b0 + bl;                  // global batch row
  const int lane = threadIdx.x & 63;
  const int d = lane;

  float npad[3];
  #pragma unroll
  for (int s=0;s<3;++s){ int id = eidx[bg*3+s]; npad[s] = (id < 0 || id == 8) ? 0.f : 1.f; }
  float denom = npad[0]+npad[1]+npad[2]; if (denom < 1.f) denom = 1.f;

  const float lam = prep[1];
  float cs[3], sn[3];
  #pragma unroll
  for (int s=0;s<3;++s){ cs[s] = prep[16 + s*64 + lane]; sn[s] = prep[256 + s*64 + lane]; }
  const float sgn = (d & 1) ? 1.f : -1.f;

  const bf16* base = qkv + (size_t)bl*3*2304;
  float qr[3][2], kr[3][2];
  #pragma unroll
  for (int s=0;s<3;++s){
    #pragma unroll
    for (int g=0; g<2; ++g){
      float qv = (d<48) ? bf2f(base[s*2304 +        (2*h+g)*48 + d]) : 0.f;
      float kv = (d<48) ? bf2f(base[s*2304 + 768 +  (2*h+g)*48 + d]) : 0.f;
      float pq = __shfl_xor(qv, 1, 64);
      float pk = __shfl_xor(kv, 1, 64);
      qr[s][g] = (d<48) ? (qv*cs[s] + sgn*pq*sn[s]) : 0.f;
      kr[s][g] = (d<48) ? (kv*cs[s] + sgn*pk*sn[s]) : 0.f;
    }
  }

  const float scale = 0.14433756729740643f;  // 48^-0.5
  float att[2][3][3];
  #pragma unroll
  for (int g=0; g<2; ++g){
    #pragma unroll
    for (int sq=0; sq<3; ++sq){
      float sc[3];
      #pragma unroll
      for (int sk=0; sk<3; ++sk){
        float pr = wred64(qr[sq][g]*kr[sk][g]);
        sc[sk] = pr*scale + (npad[sk] > 0.f ? 0.f : -1e30f);
      }
      float mx = fmaxf(sc[0], fmaxf(sc[1], sc[2]));
      float e0 = expf(sc[0]-mx), e1 = expf(sc[1]-mx), e2 = expf(sc[2]-mx);
      float inv = 1.f/(e0+e1+e2);
      att[g][sq][0]=e0*inv; att[g][sq][1]=e1*inv; att[g][sq][2]=e2*inv;
    }
  }
  float diff[3][3];
  #pragma unroll
  for (int sq=0; sq<3; ++sq)
    #pragma unroll
    for (int sk=0; sk<3; ++sk) diff[sq][sk] = att[0][sq][sk] - lam*att[1][sq][sk];

  float v0[3], v1[3];
  #pragma unroll
  for (int s=0;s<3;++s){
    v0[s] = bf2f(base[s*2304 + 1536 + h*96 + lane]);
    v1[s] = (lane<32) ? bf2f(base[s*2304 + 1536 + h*96 + 64 + lane]) : 0.f;
  }
  float sw0 = ldv<T>(subw, lane);
  float sw1 = (lane<32) ? ldv<T>(subw, 64+lane) : 0.f;

  float a0 = 0.f, a1 = 0.f;
  #pragma unroll
  for (int sq=0; sq<3; ++sq){
    float o0 = diff[sq][0]*v0[0] + diff[sq][1]*v0[1] + diff[sq][2]*v0[2];
    float o1 = diff[sq][0]*v1[0] + diff[sq][1]*v1[1] + diff[sq][2]*v1[2];
    float ss = wred64(o0*o0 + o1*o1);             // sum over 96 dims
    float rms = sqrtf(ss*(1.f/96.f) + 1e-5f);
    float kk = 0.8f / rms;                        // includes *(1-LAMBDA_INIT)
    a0 += npad[sq]*o0*kk*sw0;
    a1 += npad[sq]*o1*kk*sw1;
  }
  const float idn = 1.f/denom;
  bf16* op = obar + (size_t)bg*HID + h*96;
  op[lane] = f2bf(a0*idn);
  if (lane < 32) op[64+lane] = f2bf(a1*idn);
}

__global__ __launch_bounds__(256) void attn_kernel(
    const bf16* __restrict__ qkv, const int* __restrict__ eidx,
    const void* subw, bf16* __restrict__ obar, int b0, const float* prep)
{
  if (((const int*)prep)[0]) attn_body<bf16 >(qkv, eidx, subw, obar, b0, prep);
  else                       attn_body<float>(qkv, eidx, subw, obar, b0, prep);
}

// ---------------- launch ----------------------------------------------------
extern "C" void kernel_launch(void* const* d_in, const int* in_sizes, int n_in,
                              void* d_out, int out_size, void* d_ws, size_t ws_size,
                              hipStream_t stream)
{
  const int*  eidx = (const int*) d_in[0];
  const void* conf = d_in[1];
  const void* etab = d_in[2];
  const void* W1   = d_in[3];
  const void* b1   = d_in[4];
  const void* lng  = d_in[5];
  const void* lnb  = d_in[6];
  const void* Wq   = d_in[7];
  const void* Wk   = d_in[8];
  const void* Wv   = d_in[9];
  const void* Wo   = d_in[10];
  const void* lq1  = d_in[11];
  const void* lk1  = d_in[12];
  const void* lq2  = d_in[13];
  const void* lk2  = d_in[14];
  const void* subw = d_in[15];

  // ws layout: [prep 4KB][obar][WqkvT][WoT][hbuf][qkv]
  const size_t PREP_B = 4096ull;
  const size_t OBAR_B = 25165824ull, WQKVT_B = 3538944ull, WOT_B = 1179648ull;
  const size_t FIXED  = PREP_B + OBAR_B + WQKVT_B + WOT_B;

  char*  ws   = (char*)d_ws;
  float* prep = (float*)ws;
  bf16*  obar = (bf16*)(ws + PREP_B);
  bf16* WqkvT = (bf16*)(ws + PREP_B + OBAR_B);
  bf16* WoT   = (bf16*)(ws + PREP_B + OBAR_B + WQKVT_B);

  // largest power-of-two chunk of batch rows that fits (min 128)
  int CB = NB;
  while (CB > 128 && FIXED + (size_t)CB*18432ull > ws_size) CB >>= 1;

  bf16* hbuf = (bf16*)(ws + FIXED);
  bf16* qkv  = (bf16*)(ws + FIXED + (size_t)CB*4608ull);

  prep_kernel<<<1, 64, 0, stream>>>(etab, lq1, lk1, lq2, lk2, prep);
  transpose_weights<<<dim3(24,24,4), dim3(32,8), 0, stream>>>(Wq, Wk, Wv, Wo, WqkvT, WoT, prep);

  const int nchunks = NB / CB;
  const int ctok = 3*CB;                      // tokens per chunk (mult of 384)
  for (int c = 0; c < nchunks; ++c) {
    const int b0 = c*CB, tok0 = b0*3;
    embed_fc1_ln_gelu<<<ctok/16, 256, 0, stream>>>(eidx, conf, etab, W1, b1, lng, lnb, hbuf, tok0, prep);
    gemm_int<<<dim3(2304/128, ctok/128), 256, 0, stream>>>(hbuf, WqkvT, qkv, HID, HID, HID, 2304);
    attn_kernel<<<CB*2, 256, 0, stream>>>(qkv, eidx, subw, obar, b0, prep);
  }

  gemm_final<<<dim3(HID/128, NB/128), 256, 0, stream>>>(obar, WoT, (void*)d_out, HID, HID, HID, HID, prep);
}

// Round 6
// 618.517 us; speedup vs baseline: 1.2543x; 1.1661x over previous
//
#include <hip/hip_runtime.h>
#include <hip/hip_bf16.h>
#include <math.h>
#include <stdint.h>

typedef __hip_bfloat16 bf16;
typedef __attribute__((ext_vector_type(8))) short short8;   // 8 x bf16 (4 VGPRs)
typedef __attribute__((ext_vector_type(4))) float f32x4;

#define NB 16384
#define HID 768
#define EPS_LN 1e-5f
#define LAM_INIT 0.2f       // 0.8 - 0.6*exp(-0.3*0)

__device__ __forceinline__ float bf2f(bf16 x){ return __bfloat162float(x); }
__device__ __forceinline__ bf16  f2bf(float x){ return __float2bfloat16(x); }
__device__ __forceinline__ float bfbits(uint32_t lo16){ return __uint_as_float(lo16 << 16); }
__device__ __forceinline__ uint32_t f2bfbits(float x){
  union { float f; uint32_t u; } v; v.f = x;
  uint32_t u = v.u;
  uint32_t r = (u + 0x7fff + ((u >> 16) & 1)) >> 16;   // RNE
  return r;
}

template<typename T> __device__ __forceinline__ float ldv(const void* p, int i);
template<> __device__ __forceinline__ float ldv<float>(const void* p, int i){ return ((const float*)p)[i]; }
template<> __device__ __forceinline__ float ldv<bf16 >(const void* p, int i){ return bf2f(((const bf16*)p)[i]); }

template<typename T> __device__ __forceinline__ void stv(T* p, float v);
template<> __device__ __forceinline__ void stv<float>(float* p, float v){ *p = v; }
template<> __device__ __forceinline__ void stv<bf16 >(bf16*  p, float v){ *p = f2bf(v); }

__device__ __forceinline__ void async_copy16(void* lds, const void* g){
  __builtin_amdgcn_global_load_lds(
      (const __attribute__((address_space(1))) unsigned int*)g,
      (__attribute__((address_space(3))) unsigned int*)lds, 16, 0, 0);
}

__device__ __forceinline__ float wred64(float v){
  #pragma unroll
  for (int m = 1; m <= 32; m <<= 1) v += __shfl_xor(v, m, 64);
  return v;
}
__device__ __forceinline__ float wred32(float v){   // butterfly within each 32-lane half
  #pragma unroll
  for (int m = 1; m <= 16; m <<= 1) v += __shfl_xor(v, m, 64);
  return v;
}

// -------- prep (1 wave): dtype detect + lambda + pair-indexed RoPE tables ----
// prep floats: [0]=flag(int), [1]=lam, [16+s*32+p]=cos_p, [128+s*32+p]=sin_p (p<24)
__global__ void prep_kernel(const void* etab, const void* lq1, const void* lk1,
                            const void* lq2, const void* lk2, float* prep){
  const int lane = threadIdx.x;
  const uint32_t* p = (const uint32_t*)((const char*)etab + 512);
  int v = (lane < 16) ? (int)p[lane] : 0;
  #pragma unroll
  for (int m = 1; m <= 32; m <<= 1) v |= __shfl_xor(v, m, 64);
  const int isbf = (v == 0) ? 1 : 0;
  if (lane == 0) ((int*)prep)[0] = isbf;

  float p1 = 0.f, p2 = 0.f;
  if (lane < 48){
    if (isbf){ p1 = ldv<bf16>(lq1,lane)*ldv<bf16>(lk1,lane); p2 = ldv<bf16>(lq2,lane)*ldv<bf16>(lk2,lane); }
    else     { p1 = ldv<float>(lq1,lane)*ldv<float>(lk1,lane); p2 = ldv<float>(lq2,lane)*ldv<float>(lk2,lane); }
  }
  p1 = wred64(p1); p2 = wred64(p2);
  if (lane == 0) prep[1] = expf(p1) - expf(p2) + LAM_INIT;

  if (lane < 24){
    float invf = powf(10000.f, -(float)(2*lane)/48.f);
    #pragma unroll
    for (int s=0;s<3;++s){
      float ang = (float)s*invf;
      prep[16  + s*32 + lane] = cosf(ang);
      prep[128 + s*32 + lane] = sinf(ang);
    }
  }
}

// ---------------- weight transpose: (K,N) row-major -> bf16 (N,K) row-major --
template<typename T>
__device__ __forceinline__ void transpose_body(bf16 (*tile)[33], const void* src, bf16* dst){
  const int n0 = blockIdx.x*32, k0 = blockIdx.y*32;
  const int tx = threadIdx.x, ty = threadIdx.y;
  #pragma unroll
  for (int r=0;r<4;++r)
    tile[ty + 8*r][tx] = f2bf(ldv<T>(src, (k0 + ty + 8*r)*HID + n0 + tx));
  __syncthreads();
  #pragma unroll
  for (int r=0;r<4;++r)
    dst[(size_t)(n0 + ty + 8*r)*HID + k0 + tx] = tile[tx][ty + 8*r];
}

__global__ __launch_bounds__(256) void transpose_weights(
    const void* Wq, const void* Wk, const void* Wv, const void* Wo,
    bf16* __restrict__ WqkvT, bf16* __restrict__ WoT, const float* prep)
{
  __shared__ bf16 tile[32][33];
  const int z = blockIdx.z;
  const void* src = (z==0)? Wq : (z==1)? Wk : (z==2)? Wv : Wo;
  bf16* dst = (z<3)? (WqkvT + (size_t)z*HID*HID) : WoT;
  if (((const int*)prep)[0]) transpose_body<bf16 >(tile, src, dst);
  else                       transpose_body<float>(tile, src, dst);
}

// ---------------- fused embed -> FC1 -> LayerNorm -> exact GELU --------------
template<typename T>
__device__ __forceinline__ void embed_body(
    float (*s_emb)[32], float (*s_h)[HID],
    const int* eidx, const void* conf, const void* etab, const void* W1,
    const void* b1, const void* lng, const void* lnb, bf16* hout, int tok0)
{
  const int tid = threadIdx.x;
  const int tl0 = blockIdx.x * 16;     // chunk-local token base

  for (int i = tid; i < 16*32; i += 256) {
    int t = i >> 5, e = i & 31;
    int tt = tok0 + tl0 + t;           // global token
    int id = eidx[tt]; if (id < 0) id = 8;
    float cf = ldv<T>(conf, tt);
    s_emb[t][e] = ldv<T>(etab, id*32 + e) * cf;
  }
  __syncthreads();

  float acc0[16], acc1[16], acc2[16];
  #pragma unroll
  for (int t=0;t<16;++t){ acc0[t]=0.f; acc1[t]=0.f; acc2[t]=0.f; }
  const int c0 = tid, c1 = tid+256, c2 = tid+512;
  #pragma unroll 4
  for (int e=0;e<32;++e){
    float w0 = ldv<T>(W1, e*HID+c0), w1 = ldv<T>(W1, e*HID+c1), w2 = ldv<T>(W1, e*HID+c2);
    #pragma unroll
    for (int t=0;t<16;++t){
      float em = s_emb[t][e];
      acc0[t] += em*w0; acc1[t] += em*w1; acc2[t] += em*w2;
    }
  }
  float bb0 = ldv<T>(b1,c0), bb1 = ldv<T>(b1,c1), bb2 = ldv<T>(b1,c2);
  #pragma unroll
  for (int t=0;t<16;++t){
    s_h[t][c0] = acc0[t]+bb0; s_h[t][c1] = acc1[t]+bb1; s_h[t][c2] = acc2[t]+bb2;
  }
  __syncthreads();

  const int wv = tid>>6, lane = tid&63;
  for (int t = wv; t < 16; t += 4) {
    float x[12]; float sm = 0.f, sq = 0.f;
    #pragma unroll
    for (int j=0;j<12;++j){ float xv = s_h[t][lane + 64*j]; x[j]=xv; sm += xv; sq += xv*xv; }
    sm = wred64(sm); sq = wred64(sq);
    float mu  = sm * (1.f/768.f);
    float var = sq * (1.f/768.f) - mu*mu;
    float rs  = rsqrtf(fmaxf(var, 0.f) + EPS_LN);
    #pragma unroll
    for (int j=0;j<12;++j){
      int col = lane + 64*j;
      float y  = (x[j]-mu)*rs*ldv<T>(lng,col) + ldv<T>(lnb,col);
      float ge = 0.5f*y*(1.f + erff(y*0.70710678118f));
      hout[(size_t)(tl0+t)*HID + col] = f2bf(ge);
    }
  }
}

__global__ __launch_bounds__(256) void embed_fc1_ln_gelu(
    const int* __restrict__ eidx, const void* conf, const void* etab,
    const void* W1, const void* b1, const void* lng, const void* lnb,
    bf16* __restrict__ hout, int tok0, const float* prep)
{
  __shared__ float s_emb[16][32];
  __shared__ float s_h[16][HID];       // 48 KB
  if (((const int*)prep)[0]) embed_body<bf16 >(s_emb, s_h, eidx, conf, etab, W1, b1, lng, lnb, hout, tok0);
  else                       embed_body<float>(s_emb, s_h, eidx, conf, etab, W1, b1, lng, lnb, hout, tok0);
}

// ---------------- 128x128 MFMA GEMM, m97 staging + XCD-band swizzle ----------
// 1D grid of MT*NT blocks. xcd = bid&7 owns M-strips [xcd*MT/8, (xcd+1)*MT/8),
// walked N-fastest -> A-strip fetched by exactly one XCD; B L2-resident per XCD.
template<typename OutT>
__device__ __forceinline__ void gemm_body(
    bf16* sA, bf16* sB,
    const bf16* __restrict__ A, const bf16* __restrict__ Bt, OutT* __restrict__ C,
    int K, int lda, int ldb, int ldc, int MT, int NT)
{
  int bid = blockIdx.x;
  int mt, nt;
  if ((MT & 7) == 0) {
    int x = bid & 7, j = bid >> 3;
    nt = j % NT;
    mt = x * (MT >> 3) + j / NT;
  } else { nt = bid % NT; mt = bid / NT; }

  const int tid = threadIdx.x;
  const int wave = tid >> 6, lane = tid & 63;
  const int m0 = mt * 128, n0 = nt * 128;
  const int wm = wave >> 1, wn = wave & 1;

  f32x4 acc[4][4];
  #pragma unroll
  for (int i=0;i<4;++i)
    #pragma unroll
    for (int j=0;j<4;++j) acc[i][j] = (f32x4){0.f,0.f,0.f,0.f};

  const char* Ag = (const char*)(A  + (size_t)m0 * lda);
  const char* Bg = (const char*)(Bt + (size_t)n0 * ldb);
  const int r8  = lane >> 3;          // row within 8-row group
  const int cB  = (lane & 7) * 16;    // byte offset within row (8 lanes x 16B)

  for (int kt = 0; kt < K; kt += 64) {
    #pragma unroll
    for (int ii = 0; ii < 4; ++ii) {
      const int i = wave*4 + ii;      // 8-row group index 0..15
      const int row = i*8 + r8;
      async_copy16((char*)sA + i*1024 + lane*16, Ag + ((size_t)row*lda + kt)*2 + cB);
      async_copy16((char*)sB + i*1024 + lane*16, Bg + ((size_t)row*ldb + kt)*2 + cB);
    }
    __syncthreads();
    #pragma unroll
    for (int ks = 0; ks < 64; ks += 32) {
      const int kq = ks + (lane >> 4)*8;
      short8 af[4], bfv[4];
      #pragma unroll
      for (int i=0;i<4;++i)
        af[i]  = *(const short8*)&sA[(wm*64 + i*16 + (lane&15))*64 + kq];
      #pragma unroll
      for (int j=0;j<4;++j)
        bfv[j] = *(const short8*)&sB[(wn*64 + j*16 + (lane&15))*64 + kq];
      #pragma unroll
      for (int i=0;i<4;++i)
        #pragma unroll
        for (int j=0;j<4;++j)
          acc[i][j] = __builtin_amdgcn_mfma_f32_16x16x32_bf16(af[i], bfv[j], acc[i][j], 0,0,0);
    }
    __syncthreads();
  }

  const int rb = (lane>>4)*4, cb = lane & 15;   // C/D: col=lane&15, row=quad*4+reg
  #pragma unroll
  for (int i=0;i<4;++i)
    #pragma unroll
    for (int r=0;r<4;++r) {
      const int grow = m0 + wm*64 + i*16 + rb + r;
      OutT* Cp = C + (size_t)grow*ldc + n0 + wn*64 + cb;
      #pragma unroll
      for (int j=0;j<4;++j) stv<OutT>(Cp + j*16, acc[i][j][r]);
    }
}

__global__ __launch_bounds__(256) void gemm_int(
    const bf16* __restrict__ A, const bf16* __restrict__ Bt, bf16* __restrict__ C,
    int K, int lda, int ldb, int ldc, int MT, int NT)
{
  __shared__ __align__(16) bf16 sA[128*64];
  __shared__ __align__(16) bf16 sB[128*64];
  gemm_body<bf16>(sA, sB, A, Bt, C, K, lda, ldb, ldc, MT, NT);
}

__global__ __launch_bounds__(256) void gemm_final(
    const bf16* __restrict__ A, const bf16* __restrict__ Bt, void* C,
    int K, int lda, int ldb, int ldc, int MT, int NT, const float* prep)
{
  __shared__ __align__(16) bf16 sA[128*64];
  __shared__ __align__(16) bf16 sB[128*64];
  if (((const int*)prep)[0]) gemm_body<bf16 >(sA, sB, A, Bt, (bf16*)C,  K, lda, ldb, ldc, MT, NT);
  else                       gemm_body<float>(sA, sB, A, Bt, (float*)C, K, lda, ldb, ldc, MT, NT);
}

// ---------------- attention, pair-per-lane layout ----------------------------
// wave handles one (b, head). Lane layout:
//   q/k: half g = lane>>5, pair p = lane&31 (active p<24). Lane holds rotary
//        pair (x[2p], x[2p+1]) of the 48-dim half -> in-lane RoPE, no shfl.
//   v:   lane l<48 holds pair (v[2l], v[2l+1]) of the 96-dim head.
template<typename T>
__device__ __forceinline__ void attn_body(
    const bf16* __restrict__ qkv, const int* __restrict__ eidx,
    const void* subw, bf16* __restrict__ obar, int b0, const float* prep)
{
  const int gw = blockIdx.x*4 + (threadIdx.x>>6);
  const int bl = gw >> 3, h = gw & 7;      // chunk-local batch row, head
  const int bg = b0 + bl;                  // global batch row
  const int lane = threadIdx.x & 63;
  const int g = lane >> 5;                 // q/k half (0/1)
  const int p = lane & 31;                 // pair index within half
  const bool pa = (p < 24);

  float npad[3];
  #pragma unroll
  for (int s=0;s<3;++s){ int id = eidx[bg*3+s]; npad[s] = (id < 0 || id == 8) ? 0.f : 1.f; }
  float denom = npad[0]+npad[1]+npad[2]; if (denom < 1.f) denom = 1.f;
  const float lam = prep[1];

  float cs[3], sn[3];
  #pragma unroll
  for (int s=0;s<3;++s){
    cs[s] = pa ? prep[16  + s*32 + p] : 0.f;
    sn[s] = pa ? prep[128 + s*32 + p] : 0.f;
  }

  const char* base = (const char*)(qkv + (size_t)bl*3*2304);
  // q/k rotated pairs per token
  float qr1[3], qr2[3], kr1[3], kr2[3];
  const int qoff = (2*h+g)*48 + 2*p;       // element offset within token row
  #pragma unroll
  for (int s=0;s<3;++s){
    uint32_t qu = pa ? *(const uint32_t*)(base + (s*2304 + qoff)*2) : 0u;
    uint32_t ku = pa ? *(const uint32_t*)(base + (s*2304 + 768 + qoff)*2) : 0u;
    float q1 = bfbits(qu & 0xffff), q2 = bfbits(qu >> 16);
    float k1 = bfbits(ku & 0xffff), k2 = bfbits(ku >> 16);
    qr1[s] = q1*cs[s] - q2*sn[s];  qr2[s] = q1*sn[s] + q2*cs[s];
    kr1[s] = k1*cs[s] - k2*sn[s];  kr2[s] = k1*sn[s] + k2*cs[s];
  }

  const float scale = 0.14433756729740643f;  // 48^-0.5
  // scores for this lane's half g: reduce within 32-lane half
  float att[3][3];
  #pragma unroll
  for (int sq=0; sq<3; ++sq){
    float sc[3];
    #pragma unroll
    for (int sk=0; sk<3; ++sk){
      float pr = wred32(qr1[sq]*kr1[sk] + qr2[sq]*kr2[sk]);
      sc[sk] = pr*scale + (npad[sk] > 0.f ? 0.f : -1e30f);
    }
    float mx = fmaxf(sc[0], fmaxf(sc[1], sc[2]));
    float e0 = expf(sc[0]-mx), e1 = expf(sc[1]-mx), e2 = expf(sc[2]-mx);
    float inv = 1.f/(e0+e1+e2);
    att[sq][0]=e0*inv; att[sq][1]=e1*inv; att[sq][2]=e2*inv;
  }
  // diff = att_g0 - lam*att_g1 (uniform across wave after cross-half exchange)
  float diff[3][3];
  #pragma unroll
  for (int sq=0; sq<3; ++sq)
    #pragma unroll
    for (int sk=0; sk<3; ++sk){
      float other = __shfl_xor(att[sq][sk], 32, 64);
      diff[sq][sk] = (g==0) ? (att[sq][sk] - lam*other) : (other - lam*att[sq][sk]);
    }

  // v pairs: lane l<48 holds (v[2l], v[2l+1])
  const bool va = (lane < 48);
  float v1[3], v2[3];
  #pragma unroll
  for (int s=0;s<3;++s){
    uint32_t vu = va ? *(const uint32_t*)(base + (s*2304 + 1536 + h*96 + 2*lane)*2) : 0u;
    v1[s] = bfbits(vu & 0xffff); v2[s] = bfbits(vu >> 16);
  }
  float sw1 = va ? ldv<T>(subw, 2*lane)   : 0.f;
  float sw2 = va ? ldv<T>(subw, 2*lane+1) : 0.f;

  float a1 = 0.f, a2 = 0.f;
  #pragma unroll
  for (int sq=0; sq<3; ++sq){
    float o1 = diff[sq][0]*v1[0] + diff[sq][1]*v1[1] + diff[sq][2]*v1[2];
    float o2 = diff[sq][0]*v2[0] + diff[sq][1]*v2[1] + diff[sq][2]*v2[2];
    float ss = wred64(o1*o1 + o2*o2);             // sum over 96 dims
    float rms = sqrtf(ss*(1.f/96.f) + 1e-5f);
    float kk = 0.8f / rms;                        // includes *(1-LAMBDA_INIT)
    a1 += npad[sq]*o1*kk*sw1;
    a2 += npad[sq]*o2*kk*sw2;
  }
  const float idn = 1.f/denom;
  if (va){
    uint32_t w = f2bfbits(a1*idn) | (f2bfbits(a2*idn) << 16);
    *(uint32_t*)((char*)obar + ((size_t)bg*HID + h*96 + 2*lane)*2) = w;
  }
}

__global__ __launch_bounds__(256) void attn_kernel(
    const bf16* __restrict__ qkv, const int* __restrict__ eidx,
    const void* subw, bf16* __restrict__ obar, int b0, const float* prep)
{
  if (((const int*)prep)[0]) attn_body<bf16 >(qkv, eidx, subw, obar, b0, prep);
  else                       attn_body<float>(qkv, eidx, subw, obar, b0, prep);
}

// ---------------- launch ----------------------------------------------------
extern "C" void kernel_launch(void* const* d_in, const int* in_sizes, int n_in,
                              void* d_out, int out_size, void* d_ws, size_t ws_size,
                              hipStream_t stream)
{
  const int*  eidx = (const int*) d_in[0];
  const void* conf = d_in[1];
  const void* etab = d_in[2];
  const void* W1   = d_in[3];
  const void* b1   = d_in[4];
  const void* lng  = d_in[5];
  const void* lnb  = d_in[6];
  const void* Wq   = d_in[7];
  const void* Wk   = d_in[8];
  const void* Wv   = d_in[9];
  const void* Wo   = d_in[10];
  const void* lq1  = d_in[11];
  const void* lk1  = d_in[12];
  const void* lq2  = d_in[13];
  const void* lk2  = d_in[14];
  const void* subw = d_in[15];

  // ws layout: [prep 4KB][obar][WqkvT][WoT][hbuf][qkv]
  const size_t PREP_B = 4096ull;
  const size_t OBAR_B = 25165824ull, WQKVT_B = 3538944ull, WOT_B = 1179648ull;
  const size_t FIXED  = PREP_B + OBAR_B + WQKVT_B + WOT_B;

  char*  ws   = (char*)d_ws;
  float* prep = (float*)ws;
  bf16*  obar = (bf16*)(ws + PREP_B);
  bf16* WqkvT = (bf16*)(ws + PREP_B + OBAR_B);
  bf16* WoT   = (bf16*)(ws + PREP_B + OBAR_B + WQKVT_B);

  // largest power-of-two chunk of batch rows that fits (min 128)
  int CB = NB;
  while (CB > 128 && FIXED + (size_t)CB*18432ull > ws_size) CB >>= 1;

  bf16* hbuf = (bf16*)(ws + FIXED);
  bf16* qkv  = (bf16*)(ws + FIXED + (size_t)CB*4608ull);

  prep_kernel<<<1, 64, 0, stream>>>(etab, lq1, lk1, lq2, lk2, prep);
  transpose_weights<<<dim3(24,24,4), dim3(32,8), 0, stream>>>(Wq, Wk, Wv, Wo, WqkvT, WoT, prep);

  const int nchunks = NB / CB;
  const int ctok = 3*CB;                      // tokens per chunk (mult of 384)
  for (int c = 0; c < nchunks; ++c) {
    const int b0 = c*CB, tok0 = b0*3;
    const int MT = ctok/128, NT = 18;
    embed_fc1_ln_gelu<<<ctok/16, 256, 0, stream>>>(eidx, conf, etab, W1, b1, lng, lnb, hbuf, tok0, prep);
    gemm_int<<<MT*NT, 256, 0, stream>>>(hbuf, WqkvT, qkv, HID, HID, HID, 2304, MT, NT);
    attn_kernel<<<CB*2, 256, 0, stream>>>(qkv, eidx, subw, obar, b0, prep);
  }

  gemm_final<<<128*6, 256, 0, stream>>>(obar, WoT, (void*)d_out, HID, HID, HID, HID, 128, 6, prep);
}

// Round 7
// 610.670 us; speedup vs baseline: 1.2705x; 1.0128x over previous
//
#include <hip/hip_runtime.h>
#include <hip/hip_bf16.h>
#include <math.h>
#include <stdint.h>

typedef __hip_bfloat16 bf16;
typedef __attribute__((ext_vector_type(8))) short short8;   // 8 x bf16 (4 VGPRs)
typedef __attribute__((ext_vector_type(4))) float f32x4;

#define NB 16384
#define HID 768
#define EPS_LN 1e-5f
#define LAM_INIT 0.2f       // 0.8 - 0.6*exp(-0.3*0)

__device__ __forceinline__ float bf2f(bf16 x){ return __bfloat162float(x); }
__device__ __forceinline__ bf16  f2bf(float x){ return __float2bfloat16(x); }
__device__ __forceinline__ float bfbits(uint32_t lo16){ return __uint_as_float(lo16 << 16); }
__device__ __forceinline__ uint32_t f2bfbits(float x){
  union { float f; uint32_t u; } v; v.f = x;
  uint32_t u = v.u;
  uint32_t r = (u + 0x7fff + ((u >> 16) & 1)) >> 16;   // RNE
  return r;
}

template<typename T> __device__ __forceinline__ float ldv(const void* p, int i);
template<> __device__ __forceinline__ float ldv<float>(const void* p, int i){ return ((const float*)p)[i]; }
template<> __device__ __forceinline__ float ldv<bf16 >(const void* p, int i){ return bf2f(((const bf16*)p)[i]); }

template<typename T> __device__ __forceinline__ void stv(T* p, float v);
template<> __device__ __forceinline__ void stv<float>(float* p, float v){ *p = v; }
template<> __device__ __forceinline__ void stv<bf16 >(bf16*  p, float v){ *p = f2bf(v); }

__device__ __forceinline__ void async_copy16(void* lds, const void* g){
  __builtin_amdgcn_global_load_lds(
      (const __attribute__((address_space(1))) unsigned int*)g,
      (__attribute__((address_space(3))) unsigned int*)lds, 16, 0, 0);
}

__device__ __forceinline__ float wred64(float v){
  #pragma unroll
  for (int m = 1; m <= 32; m <<= 1) v += __shfl_xor(v, m, 64);
  return v;
}
__device__ __forceinline__ float wred32(float v){   // butterfly within each 32-lane half
  #pragma unroll
  for (int m = 1; m <= 16; m <<= 1) v += __shfl_xor(v, m, 64);
  return v;
}

// -------- prep (1 wave): dtype detect + lambda + pair-indexed RoPE tables ----
// prep floats: [0]=flag(int), [1]=lam, [16+s*32+p]=cos_p, [128+s*32+p]=sin_p (p<24)
__global__ void prep_kernel(const void* etab, const void* lq1, const void* lk1,
                            const void* lq2, const void* lk2, float* prep){
  const int lane = threadIdx.x;
  const uint32_t* p = (const uint32_t*)((const char*)etab + 512);
  int v = (lane < 16) ? (int)p[lane] : 0;
  #pragma unroll
  for (int m = 1; m <= 32; m <<= 1) v |= __shfl_xor(v, m, 64);
  const int isbf = (v == 0) ? 1 : 0;
  if (lane == 0) ((int*)prep)[0] = isbf;

  float p1 = 0.f, p2 = 0.f;
  if (lane < 48){
    if (isbf){ p1 = ldv<bf16>(lq1,lane)*ldv<bf16>(lk1,lane); p2 = ldv<bf16>(lq2,lane)*ldv<bf16>(lk2,lane); }
    else     { p1 = ldv<float>(lq1,lane)*ldv<float>(lk1,lane); p2 = ldv<float>(lq2,lane)*ldv<float>(lk2,lane); }
  }
  p1 = wred64(p1); p2 = wred64(p2);
  if (lane == 0) prep[1] = expf(p1) - expf(p2) + LAM_INIT;

  if (lane < 24){
    float invf = powf(10000.f, -(float)(2*lane)/48.f);
    #pragma unroll
    for (int s=0;s<3;++s){
      float ang = (float)s*invf;
      prep[16  + s*32 + lane] = cosf(ang);
      prep[128 + s*32 + lane] = sinf(ang);
    }
  }
}

// ---------------- weight transpose: (K,N) row-major -> bf16 (N,K) row-major --
template<typename T>
__device__ __forceinline__ void transpose_body(bf16 (*tile)[33], const void* src, bf16* dst){
  const int n0 = blockIdx.x*32, k0 = blockIdx.y*32;
  const int tx = threadIdx.x, ty = threadIdx.y;
  #pragma unroll
  for (int r=0;r<4;++r)
    tile[ty + 8*r][tx] = f2bf(ldv<T>(src, (k0 + ty + 8*r)*HID + n0 + tx));
  __syncthreads();
  #pragma unroll
  for (int r=0;r<4;++r)
    dst[(size_t)(n0 + ty + 8*r)*HID + k0 + tx] = tile[tx][ty + 8*r];
}

__global__ __launch_bounds__(256) void transpose_weights(
    const void* Wq, const void* Wk, const void* Wv, const void* Wo,
    bf16* __restrict__ WqkvT, bf16* __restrict__ WoT, const float* prep)
{
  __shared__ bf16 tile[32][33];
  const int z = blockIdx.z;
  const void* src = (z==0)? Wq : (z==1)? Wk : (z==2)? Wv : Wo;
  bf16* dst = (z<3)? (WqkvT + (size_t)z*HID*HID) : WoT;
  if (((const int*)prep)[0]) transpose_body<bf16 >(tile, src, dst);
  else                       transpose_body<float>(tile, src, dst);
}

// ---------------- fused embed -> FC1 -> LayerNorm -> exact GELU --------------
template<typename T>
__device__ __forceinline__ void embed_body(
    float (*s_emb)[32], float (*s_h)[HID],
    const int* eidx, const void* conf, const void* etab, const void* W1,
    const void* b1, const void* lng, const void* lnb, bf16* hout, int tok0)
{
  const int tid = threadIdx.x;
  const int tl0 = blockIdx.x * 16;     // chunk-local token base

  for (int i = tid; i < 16*32; i += 256) {
    int t = i >> 5, e = i & 31;
    int tt = tok0 + tl0 + t;           // global token
    int id = eidx[tt]; if (id < 0) id = 8;
    float cf = ldv<T>(conf, tt);
    s_emb[t][e] = ldv<T>(etab, id*32 + e) * cf;
  }
  __syncthreads();

  float acc0[16], acc1[16], acc2[16];
  #pragma unroll
  for (int t=0;t<16;++t){ acc0[t]=0.f; acc1[t]=0.f; acc2[t]=0.f; }
  const int c0 = tid, c1 = tid+256, c2 = tid+512;
  #pragma unroll 4
  for (int e=0;e<32;++e){
    float w0 = ldv<T>(W1, e*HID+c0), w1 = ldv<T>(W1, e*HID+c1), w2 = ldv<T>(W1, e*HID+c2);
    #pragma unroll
    for (int t=0;t<16;++t){
      float em = s_emb[t][e];
      acc0[t] += em*w0; acc1[t] += em*w1; acc2[t] += em*w2;
    }
  }
  float bb0 = ldv<T>(b1,c0), bb1 = ldv<T>(b1,c1), bb2 = ldv<T>(b1,c2);
  #pragma unroll
  for (int t=0;t<16;++t){
    s_h[t][c0] = acc0[t]+bb0; s_h[t][c1] = acc1[t]+bb1; s_h[t][c2] = acc2[t]+bb2;
  }
  __syncthreads();

  const int wv = tid>>6, lane = tid&63;
  for (int t = wv; t < 16; t += 4) {
    float x[12]; float sm = 0.f, sq = 0.f;
    #pragma unroll
    for (int j=0;j<12;++j){ float xv = s_h[t][lane + 64*j]; x[j]=xv; sm += xv; sq += xv*xv; }
    sm = wred64(sm); sq = wred64(sq);
    float mu  = sm * (1.f/768.f);
    float var = sq * (1.f/768.f) - mu*mu;
    float rs  = rsqrtf(fmaxf(var, 0.f) + EPS_LN);
    #pragma unroll
    for (int j=0;j<12;++j){
      int col = lane + 64*j;
      float y  = (x[j]-mu)*rs*ldv<T>(lng,col) + ldv<T>(lnb,col);
      float ge = 0.5f*y*(1.f + erff(y*0.70710678118f));
      hout[(size_t)(tl0+t)*HID + col] = f2bf(ge);
    }
  }
}

__global__ __launch_bounds__(256) void embed_fc1_ln_gelu(
    const int* __restrict__ eidx, const void* conf, const void* etab,
    const void* W1, const void* b1, const void* lng, const void* lnb,
    bf16* __restrict__ hout, int tok0, const float* prep)
{
  __shared__ float s_emb[16][32];
  __shared__ float s_h[16][HID];       // 48 KB
  if (((const int*)prep)[0]) embed_body<bf16 >(s_emb, s_h, eidx, conf, etab, W1, b1, lng, lnb, hout, tok0);
  else                       embed_body<float>(s_emb, s_h, eidx, conf, etab, W1, b1, lng, lnb, hout, tok0);
}

// ------- 128x128 MFMA GEMM: dbuf single-barrier pipeline + XCD swizzle -------
// Per iter: barrier (drains own cur-buf loads), prefetch next K-tile into the
// other buffer (stays in flight across the whole compute phase), 32 MFMAs.
template<typename OutT>
__device__ __forceinline__ void gemm_body(
    bf16* sA, bf16* sB,     // each 2*128*64 elements (two buffers)
    const bf16* __restrict__ A, const bf16* __restrict__ Bt, OutT* __restrict__ C,
    int K, int lda, int ldb, int ldc, int MT, int NT)
{
  int bid = blockIdx.x;
  int mt, nt;
  if ((MT & 7) == 0) {
    int x = bid & 7, j = bid >> 3;
    nt = j % NT;
    mt = x * (MT >> 3) + j / NT;
  } else { nt = bid % NT; mt = bid / NT; }

  const int tid = threadIdx.x;
  const int wave = tid >> 6, lane = tid & 63;
  const int m0 = mt * 128, n0 = nt * 128;
  const int wm = wave >> 1, wn = wave & 1;

  f32x4 acc[4][4];
  #pragma unroll
  for (int i=0;i<4;++i)
    #pragma unroll
    for (int j=0;j<4;++j) acc[i][j] = (f32x4){0.f,0.f,0.f,0.f};

  const char* Ag = (const char*)(A  + (size_t)m0 * lda);
  const char* Bg = (const char*)(Bt + (size_t)n0 * ldb);
  const int r8  = lane >> 3;          // row within 8-row group
  const int cB  = (lane & 7) * 16;    // byte offset within row (8 lanes x 16B)

  #define STAGE(buf, kt) do {                                                   \
    _Pragma("unroll")                                                           \
    for (int ii = 0; ii < 4; ++ii) {                                            \
      const int i_ = wave*4 + ii;                                               \
      const int row_ = i_*8 + r8;                                               \
      async_copy16((char*)sA + (buf)*16384 + i_*1024 + lane*16,                 \
                   Ag + ((size_t)row_*lda + (kt))*2 + cB);                      \
      async_copy16((char*)sB + (buf)*16384 + i_*1024 + lane*16,                 \
                   Bg + ((size_t)row_*ldb + (kt))*2 + cB);                      \
    }                                                                           \
  } while(0)

  STAGE(0, 0);
  int cur = 0;
  for (int kt = 0; kt < K; kt += 64) {
    __syncthreads();                  // drains this wave's cur-buf loads; syncs readers
    if (kt + 64 < K) STAGE(cur^1, kt + 64);   // prefetch overlaps compute below
    const bf16* pA = sA + cur*8192;
    const bf16* pB = sB + cur*8192;
    #pragma unroll
    for (int ks = 0; ks < 64; ks += 32) {
      const int kq = ks + (lane >> 4)*8;
      short8 af[4], bfv[4];
      #pragma unroll
      for (int i=0;i<4;++i)
        af[i]  = *(const short8*)&pA[(wm*64 + i*16 + (lane&15))*64 + kq];
      #pragma unroll
      for (int j=0;j<4;++j)
        bfv[j] = *(const short8*)&pB[(wn*64 + j*16 + (lane&15))*64 + kq];
      #pragma unroll
      for (int i=0;i<4;++i)
        #pragma unroll
        for (int j=0;j<4;++j)
          acc[i][j] = __builtin_amdgcn_mfma_f32_16x16x32_bf16(af[i], bfv[j], acc[i][j], 0,0,0);
    }
    cur ^= 1;
  }
  #undef STAGE

  const int rb = (lane>>4)*4, cb = lane & 15;   // C/D: col=lane&15, row=quad*4+reg
  #pragma unroll
  for (int i=0;i<4;++i)
    #pragma unroll
    for (int r=0;r<4;++r) {
      const int grow = m0 + wm*64 + i*16 + rb + r;
      OutT* Cp = C + (size_t)grow*ldc + n0 + wn*64 + cb;
      #pragma unroll
      for (int j=0;j<4;++j) stv<OutT>(Cp + j*16, acc[i][j][r]);
    }
}

__global__ __launch_bounds__(256) void gemm_int(
    const bf16* __restrict__ A, const bf16* __restrict__ Bt, bf16* __restrict__ C,
    int K, int lda, int ldb, int ldc, int MT, int NT)
{
  __shared__ __align__(16) bf16 sA[2*128*64];   // 32 KB
  __shared__ __align__(16) bf16 sB[2*128*64];   // 32 KB
  gemm_body<bf16>(sA, sB, A, Bt, C, K, lda, ldb, ldc, MT, NT);
}

__global__ __launch_bounds__(256) void gemm_final(
    const bf16* __restrict__ A, const bf16* __restrict__ Bt, void* C,
    int K, int lda, int ldb, int ldc, int MT, int NT, const float* prep)
{
  __shared__ __align__(16) bf16 sA[2*128*64];
  __shared__ __align__(16) bf16 sB[2*128*64];
  if (((const int*)prep)[0]) gemm_body<bf16 >(sA, sB, A, Bt, (bf16*)C,  K, lda, ldb, ldc, MT, NT);
  else                       gemm_body<float>(sA, sB, A, Bt, (float*)C, K, lda, ldb, ldc, MT, NT);
}

// ---------------- attention, pair-per-lane layout ----------------------------
template<typename T>
__device__ __forceinline__ void attn_body(
    const bf16* __restrict__ qkv, const int* __restrict__ eidx,
    const void* subw, bf16* __restrict__ obar, int b0, const float* prep)
{
  const int gw = blockIdx.x*4 + (threadIdx.x>>6);
  const int bl = gw >> 3, h = gw & 7;      // chunk-local batch row, head
  const int bg = b0 + bl;                  // global batch row
  const int lane = threadIdx.x & 63;
  const int g = lane >> 5;                 // q/k half (0/1)
  const int p = lane & 31;                 // pair index within half
  const bool pa = (p < 24);

  float npad[3];
  #pragma unroll
  for (int s=0;s<3;++s){ int id = eidx[bg*3+s]; npad[s] = (id < 0 || id == 8) ? 0.f : 1.f; }
  float denom = npad[0]+npad[1]+npad[2]; if (denom < 1.f) denom = 1.f;
  const float lam = prep[1];

  float cs[3], sn[3];
  #pragma unroll
  for (int s=0;s<3;++s){
    cs[s] = pa ? prep[16  + s*32 + p] : 0.f;
    sn[s] = pa ? prep[128 + s*32 + p] : 0.f;
  }

  const char* base = (const char*)(qkv + (size_t)bl*3*2304);
  float qr1[3], qr2[3], kr1[3], kr2[3];
  const int qoff = (2*h+g)*48 + 2*p;       // element offset within token row
  #pragma unroll
  for (int s=0;s<3;++s){
    uint32_t qu = pa ? *(const uint32_t*)(base + (s*2304 + qoff)*2) : 0u;
    uint32_t ku = pa ? *(const uint32_t*)(base + (s*2304 + 768 + qoff)*2) : 0u;
    float q1 = bfbits(qu & 0xffff), q2 = bfbits(qu >> 16);
    float k1 = bfbits(ku & 0xffff), k2 = bfbits(ku >> 16);
    qr1[s] = q1*cs[s] - q2*sn[s];  qr2[s] = q1*sn[s] + q2*cs[s];
    kr1[s] = k1*cs[s] - k2*sn[s];  kr2[s] = k1*sn[s] + k2*cs[s];
  }

  const float scale = 0.14433756729740643f;  // 48^-0.5
  float att[3][3];
  #pragma unroll
  for (int sq=0; sq<3; ++sq){
    float sc[3];
    #pragma unroll
    for (int sk=0; sk<3; ++sk){
      float pr = wred32(qr1[sq]*kr1[sk] + qr2[sq]*kr2[sk]);
      sc[sk] = pr*scale + (npad[sk] > 0.f ? 0.f : -1e30f);
    }
    float mx = fmaxf(sc[0], fmaxf(sc[1], sc[2]));
    float e0 = expf(sc[0]-mx), e1 = expf(sc[1]-mx), e2 = expf(sc[2]-mx);
    float inv = 1.f/(e0+e1+e2);
    att[sq][0]=e0*inv; att[sq][1]=e1*inv; att[sq][2]=e2*inv;
  }
  float diff[3][3];
  #pragma unroll
  for (int sq=0; sq<3; ++sq)
    #pragma unroll
    for (int sk=0; sk<3; ++sk){
      float other = __shfl_xor(att[sq][sk], 32, 64);
      diff[sq][sk] = (g==0) ? (att[sq][sk] - lam*other) : (other - lam*att[sq][sk]);
    }

  const bool va = (lane < 48);
  float v1[3], v2[3];
  #pragma unroll
  for (int s=0;s<3;++s){
    uint32_t vu = va ? *(const uint32_t*)(base + (s*2304 + 1536 + h*96 + 2*lane)*2) : 0u;
    v1[s] = bfbits(vu & 0xffff); v2[s] = bfbits(vu >> 16);
  }
  float sw1 = va ? ldv<T>(subw, 2*lane)   : 0.f;
  float sw2 = va ? ldv<T>(subw, 2*lane+1) : 0.f;

  float a1 = 0.f, a2 = 0.f;
  #pragma unroll
  for (int sq=0; sq<3; ++sq){
    float o1 = diff[sq][0]*v1[0] + diff[sq][1]*v1[1] + diff[sq][2]*v1[2];
    float o2 = diff[sq][0]*v2[0] + diff[sq][1]*v2[1] + diff[sq][2]*v2[2];
    float ss = wred64(o1*o1 + o2*o2);             // sum over 96 dims
    float rms = sqrtf(ss*(1.f/96.f) + 1e-5f);
    float kk = 0.8f / rms;                        // includes *(1-LAMBDA_INIT)
    a1 += npad[sq]*o1*kk*sw1;
    a2 += npad[sq]*o2*kk*sw2;
  }
  const float idn = 1.f/denom;
  if (va){
    uint32_t w = f2bfbits(a1*idn) | (f2bfbits(a2*idn) << 16);
    *(uint32_t*)((char*)obar + ((size_t)bg*HID + h*96 + 2*lane)*2) = w;
  }
}

__global__ __launch_bounds__(256) void attn_kernel(
    const bf16* __restrict__ qkv, const int* __restrict__ eidx,
    const void* subw, bf16* __restrict__ obar, int b0, const float* prep)
{
  if (((const int*)prep)[0]) attn_body<bf16 >(qkv, eidx, subw, obar, b0, prep);
  else                       attn_body<float>(qkv, eidx, subw, obar, b0, prep);
}

// ---------------- launch ----------------------------------------------------
extern "C" void kernel_launch(void* const* d_in, const int* in_sizes, int n_in,
                              void* d_out, int out_size, void* d_ws, size_t ws_size,
                              hipStream_t stream)
{
  const int*  eidx = (const int*) d_in[0];
  const void* conf = d_in[1];
  const void* etab = d_in[2];
  const void* W1   = d_in[3];
  const void* b1   = d_in[4];
  const void* lng  = d_in[5];
  const void* lnb  = d_in[6];
  const void* Wq   = d_in[7];
  const void* Wk   = d_in[8];
  const void* Wv   = d_in[9];
  const void* Wo   = d_in[10];
  const void* lq1  = d_in[11];
  const void* lk1  = d_in[12];
  const void* lq2  = d_in[13];
  const void* lk2  = d_in[14];
  const void* subw = d_in[15];

  // ws layout: [prep 4KB][obar][WqkvT][WoT][hbuf][qkv]
  const size_t PREP_B = 4096ull;
  const size_t OBAR_B = 25165824ull, WQKVT_B = 3538944ull, WOT_B = 1179648ull;
  const size_t FIXED  = PREP_B + OBAR_B + WQKVT_B + WOT_B;

  char*  ws   = (char*)d_ws;
  float* prep = (float*)ws;
  bf16*  obar = (bf16*)(ws + PREP_B);
  bf16* WqkvT = (bf16*)(ws + PREP_B + OBAR_B);
  bf16* WoT   = (bf16*)(ws + PREP_B + OBAR_B + WQKVT_B);

  // largest power-of-two chunk of batch rows that fits (min 128)
  int CB = NB;
  while (CB > 128 && FIXED + (size_t)CB*18432ull > ws_size) CB >>= 1;

  bf16* hbuf = (bf16*)(ws + FIXED);
  bf16* qkv  = (bf16*)(ws + FIXED + (size_t)CB*4608ull);

  prep_kernel<<<1, 64, 0, stream>>>(etab, lq1, lk1, lq2, lk2, prep);
  transpose_weights<<<dim3(24,24,4), dim3(32,8), 0, stream>>>(Wq, Wk, Wv, Wo, WqkvT, WoT, prep);

  const int nchunks = NB / CB;
  const int ctok = 3*CB;                      // tokens per chunk (mult of 384)
  for (int c = 0; c < nchunks; ++c) {
    const int b0 = c*CB, tok0 = b0*3;
    const int MT = ctok/128, NT = 18;
    embed_fc1_ln_gelu<<<ctok/16, 256, 0, stream>>>(eidx, conf, etab, W1, b1, lng, lnb, hbuf, tok0, prep);
    gemm_int<<<MT*NT, 256, 0, stream>>>(hbuf, WqkvT, qkv, HID, HID, HID, 2304, MT, NT);
    attn_kernel<<<CB*2, 256, 0, stream>>>(qkv, eidx, subw, obar, b0, prep);
  }

  gemm_final<<<128*6, 256, 0, stream>>>(obar, WoT, (void*)d_out, HID, HID, HID, HID, 128, 6, prep);
}

// Round 8
// 546.657 us; speedup vs baseline: 1.4192x; 1.1171x over previous
//
#include <hip/hip_runtime.h>
#include <hip/hip_bf16.h>
#include <math.h>
#include <stdint.h>

typedef __hip_bfloat16 bf16;
typedef __attribute__((ext_vector_type(8))) short short8;   // 8 x bf16 (4 VGPRs)
typedef __attribute__((ext_vector_type(4))) float f32x4;

#define NB 16384
#define HID 768
#define EPS_LN 1e-5f
#define LAM_INIT 0.2f       // 0.8 - 0.6*exp(-0.3*0)

__device__ __forceinline__ float bf2f(bf16 x){ return __bfloat162float(x); }
__device__ __forceinline__ bf16  f2bf(float x){ return __float2bfloat16(x); }
__device__ __forceinline__ float bfbits(uint32_t lo16){ return __uint_as_float(lo16 << 16); }
__device__ __forceinline__ uint32_t f2bfbits(float x){
  union { float f; uint32_t u; } v; v.f = x;
  uint32_t u = v.u;
  uint32_t r = (u + 0x7fff + ((u >> 16) & 1)) >> 16;   // RNE
  return r;
}

template<typename T> __device__ __forceinline__ float ldv(const void* p, int i);
template<> __device__ __forceinline__ float ldv<float>(const void* p, int i){ return ((const float*)p)[i]; }
template<> __device__ __forceinline__ float ldv<bf16 >(const void* p, int i){ return bf2f(((const bf16*)p)[i]); }

template<typename T> __device__ __forceinline__ void stv(T* p, float v);
template<> __device__ __forceinline__ void stv<float>(float* p, float v){ *p = v; }
template<> __device__ __forceinline__ void stv<bf16 >(bf16*  p, float v){ *p = f2bf(v); }

__device__ __forceinline__ void async_copy16(void* lds, const void* g){
  __builtin_amdgcn_global_load_lds(
      (const __attribute__((address_space(1))) unsigned int*)g,
      (__attribute__((address_space(3))) unsigned int*)lds, 16, 0, 0);
}

__device__ __forceinline__ float wred64(float v){
  #pragma unroll
  for (int m = 1; m <= 32; m <<= 1) v += __shfl_xor(v, m, 64);
  return v;
}
__device__ __forceinline__ float wred32(float v){   // butterfly within each 32-lane half
  #pragma unroll
  for (int m = 1; m <= 16; m <<= 1) v += __shfl_xor(v, m, 64);
  return v;
}

// -------- prep (1 wave): dtype detect + lambda + pair-indexed RoPE tables ----
// prep floats: [0]=flag(int), [1]=lam, [16+s*32+p]=cos_p, [128+s*32+p]=sin_p (p<24)
__global__ void prep_kernel(const void* etab, const void* lq1, const void* lk1,
                            const void* lq2, const void* lk2, float* prep){
  const int lane = threadIdx.x;
  const uint32_t* p = (const uint32_t*)((const char*)etab + 512);
  int v = (lane < 16) ? (int)p[lane] : 0;
  #pragma unroll
  for (int m = 1; m <= 32; m <<= 1) v |= __shfl_xor(v, m, 64);
  const int isbf = (v == 0) ? 1 : 0;
  if (lane == 0) ((int*)prep)[0] = isbf;

  float p1 = 0.f, p2 = 0.f;
  if (lane < 48){
    if (isbf){ p1 = ldv<bf16>(lq1,lane)*ldv<bf16>(lk1,lane); p2 = ldv<bf16>(lq2,lane)*ldv<bf16>(lk2,lane); }
    else     { p1 = ldv<float>(lq1,lane)*ldv<float>(lk1,lane); p2 = ldv<float>(lq2,lane)*ldv<float>(lk2,lane); }
  }
  p1 = wred64(p1); p2 = wred64(p2);
  if (lane == 0) prep[1] = expf(p1) - expf(p2) + LAM_INIT;

  if (lane < 24){
    float invf = powf(10000.f, -(float)(2*lane)/48.f);
    #pragma unroll
    for (int s=0;s<3;++s){
      float ang = (float)s*invf;
      prep[16  + s*32 + lane] = cosf(ang);
      prep[128 + s*32 + lane] = sinf(ang);
    }
  }
}

// ---------------- weight transpose: (K,N) row-major -> bf16 (N,K) row-major --
template<typename T>
__device__ __forceinline__ void transpose_body(bf16 (*tile)[33], const void* src, bf16* dst){
  const int n0 = blockIdx.x*32, k0 = blockIdx.y*32;
  const int tx = threadIdx.x, ty = threadIdx.y;
  #pragma unroll
  for (int r=0;r<4;++r)
    tile[ty + 8*r][tx] = f2bf(ldv<T>(src, (k0 + ty + 8*r)*HID + n0 + tx));
  __syncthreads();
  #pragma unroll
  for (int r=0;r<4;++r)
    dst[(size_t)(n0 + ty + 8*r)*HID + k0 + tx] = tile[tx][ty + 8*r];
}

__global__ __launch_bounds__(256) void transpose_weights(
    const void* Wq, const void* Wk, const void* Wv, const void* Wo,
    bf16* __restrict__ WqkvT, bf16* __restrict__ WoT, const float* prep)
{
  __shared__ bf16 tile[32][33];
  const int z = blockIdx.z;
  const void* src = (z==0)? Wq : (z==1)? Wk : (z==2)? Wv : Wo;
  bf16* dst = (z<3)? (WqkvT + (size_t)z*HID*HID) : WoT;
  if (((const int*)prep)[0]) transpose_body<bf16 >(tile, src, dst);
  else                       transpose_body<float>(tile, src, dst);
}

// ---------------- fused embed -> FC1 -> LayerNorm -> exact GELU --------------
template<typename T>
__device__ __forceinline__ void embed_body(
    float (*s_emb)[32], float (*s_h)[HID],
    const int* eidx, const void* conf, const void* etab, const void* W1,
    const void* b1, const void* lng, const void* lnb, bf16* hout, int tok0)
{
  const int tid = threadIdx.x;
  const int tl0 = blockIdx.x * 16;     // chunk-local token base

  for (int i = tid; i < 16*32; i += 256) {
    int t = i >> 5, e = i & 31;
    int tt = tok0 + tl0 + t;           // global token
    int id = eidx[tt]; if (id < 0) id = 8;
    float cf = ldv<T>(conf, tt);
    s_emb[t][e] = ldv<T>(etab, id*32 + e) * cf;
  }
  __syncthreads();

  float acc0[16], acc1[16], acc2[16];
  #pragma unroll
  for (int t=0;t<16;++t){ acc0[t]=0.f; acc1[t]=0.f; acc2[t]=0.f; }
  const int c0 = tid, c1 = tid+256, c2 = tid+512;
  #pragma unroll 4
  for (int e=0;e<32;++e){
    float w0 = ldv<T>(W1, e*HID+c0), w1 = ldv<T>(W1, e*HID+c1), w2 = ldv<T>(W1, e*HID+c2);
    #pragma unroll
    for (int t=0;t<16;++t){
      float em = s_emb[t][e];
      acc0[t] += em*w0; acc1[t] += em*w1; acc2[t] += em*w2;
    }
  }
  float bb0 = ldv<T>(b1,c0), bb1 = ldv<T>(b1,c1), bb2 = ldv<T>(b1,c2);
  #pragma unroll
  for (int t=0;t<16;++t){
    s_h[t][c0] = acc0[t]+bb0; s_h[t][c1] = acc1[t]+bb1; s_h[t][c2] = acc2[t]+bb2;
  }
  __syncthreads();

  const int wv = tid>>6, lane = tid&63;
  for (int t = wv; t < 16; t += 4) {
    float x[12]; float sm = 0.f, sq = 0.f;
    #pragma unroll
    for (int j=0;j<12;++j){ float xv = s_h[t][lane + 64*j]; x[j]=xv; sm += xv; sq += xv*xv; }
    sm = wred64(sm); sq = wred64(sq);
    float mu  = sm * (1.f/768.f);
    float var = sq * (1.f/768.f) - mu*mu;
    float rs  = rsqrtf(fmaxf(var, 0.f) + EPS_LN);
    #pragma unroll
    for (int j=0;j<12;++j){
      int col = lane + 64*j;
      float y  = (x[j]-mu)*rs*ldv<T>(lng,col) + ldv<T>(lnb,col);
      float ge = 0.5f*y*(1.f + erff(y*0.70710678118f));
      hout[(size_t)(tl0+t)*HID + col] = f2bf(ge);
    }
  }
}

__global__ __launch_bounds__(256) void embed_fc1_ln_gelu(
    const int* __restrict__ eidx, const void* conf, const void* etab,
    const void* W1, const void* b1, const void* lng, const void* lnb,
    bf16* __restrict__ hout, int tok0, const float* prep)
{
  __shared__ float s_emb[16][32];
  __shared__ float s_h[16][HID];       // 48 KB
  if (((const int*)prep)[0]) embed_body<bf16 >(s_emb, s_h, eidx, conf, etab, W1, b1, lng, lnb, hout, tok0);
  else                       embed_body<float>(s_emb, s_h, eidx, conf, etab, W1, b1, lng, lnb, hout, tok0);
}

// ------- 128x128 MFMA GEMM: dbuf pipeline + XCD swizzle + LDS XOR swizzle ----
// Bank-conflict fix: logical k-group g of row r is stored at phys group
// g ^ (r&7). Staging keeps the HW-required linear LDS dest (base+lane*16) and
// permutes the GLOBAL source k-group instead (same 128B segment -> coalesced).
// Readers XOR their k-offset with (row&7)*8. Quad lanes then hit 8 distinct
// bank groups, 2 lanes each (2-way = free, m136) instead of 16-way.
template<typename OutT>
__device__ __forceinline__ void gemm_body(
    bf16* sA, bf16* sB,     // each 2*128*64 elements (two buffers)
    const bf16* __restrict__ A, const bf16* __restrict__ Bt, OutT* __restrict__ C,
    int K, int lda, int ldb, int ldc, int MT, int NT)
{
  int bid = blockIdx.x;
  int mt, nt;
  if ((MT & 7) == 0) {
    int x = bid & 7, j = bid >> 3;
    nt = j % NT;
    mt = x * (MT >> 3) + j / NT;
  } else { nt = bid % NT; mt = bid / NT; }

  const int tid = threadIdx.x;
  const int wave = tid >> 6, lane = tid & 63;
  const int m0 = mt * 128, n0 = nt * 128;
  const int wm = wave >> 1, wn = wave & 1;

  f32x4 acc[4][4];
  #pragma unroll
  for (int i=0;i<4;++i)
    #pragma unroll
    for (int j=0;j<4;++j) acc[i][j] = (f32x4){0.f,0.f,0.f,0.f};

  const char* Ag = (const char*)(A  + (size_t)m0 * lda);
  const char* Bg = (const char*)(Bt + (size_t)n0 * ldb);
  const int r8  = lane >> 3;                       // row within 8-row group (0..7)
  const int cBx = ((lane & 7) ^ r8) * 16;          // XOR-permuted k-group source

  #define STAGE(buf, kt) do {                                                   \
    _Pragma("unroll")                                                           \
    for (int ii = 0; ii < 4; ++ii) {                                            \
      const int i_ = wave*4 + ii;                                               \
      const int row_ = i_*8 + r8;                                               \
      async_copy16((char*)sA + (buf)*16384 + i_*1024 + lane*16,                 \
                   Ag + ((size_t)row_*lda + (kt))*2 + cBx);                     \
      async_copy16((char*)sB + (buf)*16384 + i_*1024 + lane*16,                 \
                   Bg + ((size_t)row_*ldb + (kt))*2 + cBx);                     \
    }                                                                           \
  } while(0)

  STAGE(0, 0);
  int cur = 0;
  const int rxor = (lane & 7) << 3;                // reader phys-k XOR (row&7)*8
  for (int kt = 0; kt < K; kt += 64) {
    __syncthreads();
    if (kt + 64 < K) STAGE(cur^1, kt + 64);   // prefetch overlaps compute below
    const bf16* pA = sA + cur*8192;
    const bf16* pB = sB + cur*8192;
    #pragma unroll
    for (int ks = 0; ks < 64; ks += 32) {
      const int kq = (ks + (lane >> 4)*8) ^ rxor;
      short8 af[4], bfv[4];
      #pragma unroll
      for (int i=0;i<4;++i)
        af[i]  = *(const short8*)&pA[(wm*64 + i*16 + (lane&15))*64 + kq];
      #pragma unroll
      for (int j=0;j<4;++j)
        bfv[j] = *(const short8*)&pB[(wn*64 + j*16 + (lane&15))*64 + kq];
      #pragma unroll
      for (int i=0;i<4;++i)
        #pragma unroll
        for (int j=0;j<4;++j)
          acc[i][j] = __builtin_amdgcn_mfma_f32_16x16x32_bf16(af[i], bfv[j], acc[i][j], 0,0,0);
    }
    cur ^= 1;
  }
  #undef STAGE

  const int rb = (lane>>4)*4, cb = lane & 15;   // C/D: col=lane&15, row=quad*4+reg
  #pragma unroll
  for (int i=0;i<4;++i)
    #pragma unroll
    for (int r=0;r<4;++r) {
      const int grow = m0 + wm*64 + i*16 + rb + r;
      OutT* Cp = C + (size_t)grow*ldc + n0 + wn*64 + cb;
      #pragma unroll
      for (int j=0;j<4;++j) stv<OutT>(Cp + j*16, acc[i][j][r]);
    }
}

__global__ __launch_bounds__(256) void gemm_int(
    const bf16* __restrict__ A, const bf16* __restrict__ Bt, bf16* __restrict__ C,
    int K, int lda, int ldb, int ldc, int MT, int NT)
{
  __shared__ __align__(16) bf16 sA[2*128*64];   // 32 KB
  __shared__ __align__(16) bf16 sB[2*128*64];   // 32 KB
  gemm_body<bf16>(sA, sB, A, Bt, C, K, lda, ldb, ldc, MT, NT);
}

__global__ __launch_bounds__(256) void gemm_final(
    const bf16* __restrict__ A, const bf16* __restrict__ Bt, void* C,
    int K, int lda, int ldb, int ldc, int MT, int NT, const float* prep)
{
  __shared__ __align__(16) bf16 sA[2*128*64];
  __shared__ __align__(16) bf16 sB[2*128*64];
  if (((const int*)prep)[0]) gemm_body<bf16 >(sA, sB, A, Bt, (bf16*)C,  K, lda, ldb, ldc, MT, NT);
  else                       gemm_body<float>(sA, sB, A, Bt, (float*)C, K, lda, ldb, ldc, MT, NT);
}

// ---------------- attention, pair-per-lane layout ----------------------------
template<typename T>
__device__ __forceinline__ void attn_body(
    const bf16* __restrict__ qkv, const int* __restrict__ eidx,
    const void* subw, bf16* __restrict__ obar, int b0, const float* prep)
{
  const int gw = blockIdx.x*4 + (threadIdx.x>>6);
  const int bl = gw >> 3, h = gw & 7;      // chunk-local batch row, head
  const int bg = b0 + bl;                  // global batch row
  const int lane = threadIdx.x & 63;
  const int g = lane >> 5;                 // q/k half (0/1)
  const int p = lane & 31;                 // pair index within half
  const bool pa = (p < 24);

  float npad[3];
  #pragma unroll
  for (int s=0;s<3;++s){ int id = eidx[bg*3+s]; npad[s] = (id < 0 || id == 8) ? 0.f : 1.f; }
  float denom = npad[0]+npad[1]+npad[2]; if (denom < 1.f) denom = 1.f;
  const float lam = prep[1];

  float cs[3], sn[3];
  #pragma unroll
  for (int s=0;s<3;++s){
    cs[s] = pa ? prep[16  + s*32 + p] : 0.f;
    sn[s] = pa ? prep[128 + s*32 + p] : 0.f;
  }

  const char* base = (const char*)(qkv + (size_t)bl*3*2304);
  float qr1[3], qr2[3], kr1[3], kr2[3];
  const int qoff = (2*h+g)*48 + 2*p;       // element offset within token row
  #pragma unroll
  for (int s=0;s<3;++s){
    uint32_t qu = pa ? *(const uint32_t*)(base + (s*2304 + qoff)*2) : 0u;
    uint32_t ku = pa ? *(const uint32_t*)(base + (s*2304 + 768 + qoff)*2) : 0u;
    float q1 = bfbits(qu & 0xffff), q2 = bfbits(qu >> 16);
    float k1 = bfbits(ku & 0xffff), k2 = bfbits(ku >> 16);
    qr1[s] = q1*cs[s] - q2*sn[s];  qr2[s] = q1*sn[s] + q2*cs[s];
    kr1[s] = k1*cs[s] - k2*sn[s];  kr2[s] = k1*sn[s] + k2*cs[s];
  }

  const float scale = 0.14433756729740643f;  // 48^-0.5
  float att[3][3];
  #pragma unroll
  for (int sq=0; sq<3; ++sq){
    float sc[3];
    #pragma unroll
    for (int sk=0; sk<3; ++sk){
      float pr = wred32(qr1[sq]*kr1[sk] + qr2[sq]*kr2[sk]);
      sc[sk] = pr*scale + (npad[sk] > 0.f ? 0.f : -1e30f);
    }
    float mx = fmaxf(sc[0], fmaxf(sc[1], sc[2]));
    float e0 = expf(sc[0]-mx), e1 = expf(sc[1]-mx), e2 = expf(sc[2]-mx);
    float inv = 1.f/(e0+e1+e2);
    att[sq][0]=e0*inv; att[sq][1]=e1*inv; att[sq][2]=e2*inv;
  }
  float diff[3][3];
  #pragma unroll
  for (int sq=0; sq<3; ++sq)
    #pragma unroll
    for (int sk=0; sk<3; ++sk){
      float other = __shfl_xor(att[sq][sk], 32, 64);
      diff[sq][sk] = (g==0) ? (att[sq][sk] - lam*other) : (other - lam*att[sq][sk]);
    }

  const bool va = (lane < 48);
  float v1[3], v2[3];
  #pragma unroll
  for (int s=0;s<3;++s){
    uint32_t vu = va ? *(const uint32_t*)(base + (s*2304 + 1536 + h*96 + 2*lane)*2) : 0u;
    v1[s] = bfbits(vu & 0xffff); v2[s] = bfbits(vu >> 16);
  }
  float sw1 = va ? ldv<T>(subw, 2*lane)   : 0.f;
  float sw2 = va ? ldv<T>(subw, 2*lane+1) : 0.f;

  float a1 = 0.f, a2 = 0.f;
  #pragma unroll
  for (int sq=0; sq<3; ++sq){
    float o1 = diff[sq][0]*v1[0] + diff[sq][1]*v1[1] + diff[sq][2]*v1[2];
    float o2 = diff[sq][0]*v2[0] + diff[sq][1]*v2[1] + diff[sq][2]*v2[2];
    float ss = wred64(o1*o1 + o2*o2);             // sum over 96 dims
    float rms = sqrtf(ss*(1.f/96.f) + 1e-5f);
    float kk = 0.8f / rms;                        // includes *(1-LAMBDA_INIT)
    a1 += npad[sq]*o1*kk*sw1;
    a2 += npad[sq]*o2*kk*sw2;
  }
  const float idn = 1.f/denom;
  if (va){
    uint32_t w = f2bfbits(a1*idn) | (f2bfbits(a2*idn) << 16);
    *(uint32_t*)((char*)obar + ((size_t)bg*HID + h*96 + 2*lane)*2) = w;
  }
}

__global__ __launch_bounds__(256) void attn_kernel(
    const bf16* __restrict__ qkv, const int* __restrict__ eidx,
    const void* subw, bf16* __restrict__ obar, int b0, const float* prep)
{
  if (((const int*)prep)[0]) attn_body<bf16 >(qkv, eidx, subw, obar, b0, prep);
  else                       attn_body<float>(qkv, eidx, subw, obar, b0, prep);
}

// ---------------- launch ----------------------------------------------------
extern "C" void kernel_launch(void* const* d_in, const int* in_sizes, int n_in,
                              void* d_out, int out_size, void* d_ws, size_t ws_size,
                              hipStream_t stream)
{
  const int*  eidx = (const int*) d_in[0];
  const void* conf = d_in[1];
  const void* etab = d_in[2];
  const void* W1   = d_in[3];
  const void* b1   = d_in[4];
  const void* lng  = d_in[5];
  const void* lnb  = d_in[6];
  const void* Wq   = d_in[7];
  const void* Wk   = d_in[8];
  const void* Wv   = d_in[9];
  const void* Wo   = d_in[10];
  const void* lq1  = d_in[11];
  const void* lk1  = d_in[12];
  const void* lq2  = d_in[13];
  const void* lk2  = d_in[14];
  const void* subw = d_in[15];

  // ws layout: [prep 4KB][obar][WqkvT][WoT][hbuf][qkv]
  const size_t PREP_B = 4096ull;
  const size_t OBAR_B = 25165824ull, WQKVT_B = 3538944ull, WOT_B = 1179648ull;
  const size_t FIXED  = PREP_B + OBAR_B + WQKVT_B + WOT_B;

  char*  ws   = (char*)d_ws;
  float* prep = (float*)ws;
  bf16*  obar = (bf16*)(ws + PREP_B);
  bf16* WqkvT = (bf16*)(ws + PREP_B + OBAR_B);
  bf16* WoT   = (bf16*)(ws + PREP_B + OBAR_B + WQKVT_B);

  // largest power-of-two chunk of batch rows that fits (min 128)
  int CB = NB;
  while (CB > 128 && FIXED + (size_t)CB*18432ull > ws_size) CB >>= 1;

  bf16* hbuf = (bf16*)(ws + FIXED);
  bf16* qkv  = (bf16*)(ws + FIXED + (size_t)CB*4608ull);

  prep_kernel<<<1, 64, 0, stream>>>(etab, lq1, lk1, lq2, lk2, prep);
  transpose_weights<<<dim3(24,24,4), dim3(32,8), 0, stream>>>(Wq, Wk, Wv, Wo, WqkvT, WoT, prep);

  const int nchunks = NB / CB;
  const int ctok = 3*CB;                      // tokens per chunk (mult of 384)
  for (int c = 0; c < nchunks; ++c) {
    const int b0 = c*CB, tok0 = b0*3;
    const int MT = ctok/128, NT = 18;
    embed_fc1_ln_gelu<<<ctok/16, 256, 0, stream>>>(eidx, conf, etab, W1, b1, lng, lnb, hbuf, tok0, prep);
    gemm_int<<<MT*NT, 256, 0, stream>>>(hbuf, WqkvT, qkv, HID, HID, HID, 2304, MT, NT);
    attn_kernel<<<CB*2, 256, 0, stream>>>(qkv, eidx, subw, obar, b0, prep);
  }

  gemm_final<<<128*6, 256, 0, stream>>>(obar, WoT, (void*)d_out, HID, HID, HID, HID, 128, 6, prep);
}